// Round 15
// baseline (570.749 us; speedup 1.0000x reference)
//
#include <hip/hip_runtime.h>

typedef unsigned char u8;
typedef unsigned short u16;
typedef unsigned int u32;
typedef float f32x4 __attribute__((ext_vector_type(4)));
typedef u32 u32x4 __attribute__((ext_vector_type(4)));
typedef __bf16 bf16x8 __attribute__((ext_vector_type(8)));

#define DEV __device__ __forceinline__

DEV u16 f2bf(float f) {
  u32 u = __builtin_bit_cast(u32, f);
  u += 0x7fffu + ((u >> 16) & 1u);
  return (u16)(u >> 16);
}
DEV float bf2f(u16 u) { return __builtin_bit_cast(float, (u32)u << 16); }

// f32 -> OCP e4m3fn: hardware cvt_pk when available, software RNE fallback
#if __has_builtin(__builtin_amdgcn_cvt_pk_fp8_f32)
DEV u32 pk4f8(float x, float y, float z, float w) {
  int v = 0;
  v = __builtin_amdgcn_cvt_pk_fp8_f32(x, y, v, false);
  v = __builtin_amdgcn_cvt_pk_fp8_f32(z, w, v, true);
  return (u32)v;
}
DEV u32 f2f8(float f) {
  return (u32)(__builtin_amdgcn_cvt_pk_fp8_f32(f, f, 0, false) & 0xff);
}
#else
DEV u32 f2f8(float f) {
  u32 u = __builtin_bit_cast(u32, f);
  u32 s = (u >> 31) << 7;
  float a = __builtin_fabsf(f);
  if (a >= 448.f) return s | 0x7Eu;
  if (a < 0.015625f) {
    int m = (int)(a * 512.f + 0.5f);
    return s | (u32)m;
  }
  u32 b = __builtin_bit_cast(u32, a);
  b += 0x7FFFFu + ((b >> 20) & 1u);
  u32 E = (b >> 23) - 120u;
  if (E > 15u) return s | 0x7Eu;
  return s | (E << 3) | ((b >> 20) & 7u);
}
DEV u32 pk4f8(float x, float y, float z, float w) {
  return f2f8(x) | (f2f8(y) << 8) | (f2f8(z) << 16) | (f2f8(w) << 24);
}
#endif

DEV f32x4 ldnt4(const float* p) {
  return __builtin_nontemporal_load((const f32x4*)p);
}
DEV void stnt4(u8* p, u32x4 v) {
  __builtin_nontemporal_store(v, (u32x4*)p);
}

DEV float waveAllSum(float x) {
#pragma unroll
  for (int off = 32; off > 0; off >>= 1) x += __shfl_xor(x, off, 64);
  return x;
}
DEV float silu_f(float x) { return x / (1.f + __expf(-x)); }

DEV void gll16(const void* g, void* l) {
  __builtin_amdgcn_global_load_lds(
      (const __attribute__((address_space(1))) void*)g,
      (__attribute__((address_space(3))) void*)l, 16, 0, 0);
}

// ---------------------------------------------------------------------------
// FP8 GEMM: C = A_fp8[m,k] * (16*W)_fp8[n,k]^T * (1/16); BM x BN tile,
// BK=128, 4 waves (2x2), dbuf global_load_lds + counted vmcnt.
// LDS rows 128B as long[16]; 16B-chunk XOR swizzle by row&7 on global SOURCE
// (linear LDS dest, rule #21) and on the ds_read index.
// EPI: 1 = residual RX += gm*(acc*S+bias); 2 = qk-RMSNorm+RoPE+v -> bf16
// q/k/v; 3 = SwiGLU pair-fuse -> h1 fp8 (w1/w3 interleaved 16-unit groups).
// ---------------------------------------------------------------------------
template<int BM, int BN, int EPI>
__global__ __launch_bounds__(256, (BM == 128 ? 2 : ((BM + BN) == 128 ? 4 : 3)))
void gemm8_t(
    const u8* __restrict__ A, int lda,
    const u8* __restrict__ W, int ldw,
    int Ksteps, int nbx,
    float* __restrict__ RX, const float* __restrict__ gmods,
    const float* __restrict__ bias,
    u16* __restrict__ ob0, u16* __restrict__ ob1, u16* __restrict__ ob2,
    u8* __restrict__ h1o,
    const float* __restrict__ nw_q, const float* __restrict__ nw_k)
{
  constexpr int MI = BM / 32;           // 16-row acc tiles per wave
  constexpr int NJ = BN / 32;           // 16-col acc tiles per wave
  constexpr int LOADS = (BM + BN) / 32; // gll16 per lane per stage
  __shared__ long As[2][BM][16];
  __shared__ long Ws[2][BN][16];
  const int tid = threadIdx.x;
  const int lane = tid & 63;
  const int wave = tid >> 6;
  const int nwg = gridDim.x;
  const int cpx = nwg >> 3;
  const int fb = blockIdx.x;
  const int idx = (fb & 7) * cpx + (fb >> 3);
  const int m0 = (idx % nbx) * BM;
  const int n0 = (idx / nbx) * BN;
  const int wm = (wave >> 1) * (BM / 2);
  const int wn = (wave & 1) * (BN / 2);
  const int rl = lane & 15;
  const int qq = lane >> 4;            // 0..3
  const u8* Abase = A + (size_t)m0 * lda;
  const u8* Wbase = W + (size_t)n0 * ldw;

  f32x4 acc[MI][NJ];
#pragma unroll
  for (int i = 0; i < MI; ++i)
#pragma unroll
    for (int j = 0; j < NJ; ++j) acc[i][j] = (f32x4){0.f, 0.f, 0.f, 0.f};

  auto STAGE = [&](int buf, int k0) {
#pragma unroll
    for (int c = 0; c < BM / 32; ++c) {
      const int flat = c * 256 + tid;
      const int row = flat >> 3;
      const int ch = flat & 7;
      gll16(Abase + (size_t)row * lda + k0 + ((ch ^ (row & 7)) << 4),
            &As[buf][row][ch * 2]);
    }
#pragma unroll
    for (int c = 0; c < BN / 32; ++c) {
      const int flat = c * 256 + tid;
      const int row = flat >> 3;
      const int ch = flat & 7;
      gll16(Wbase + (size_t)row * ldw + k0 + ((ch ^ (row & 7)) << 4),
            &Ws[buf][row][ch * 2]);
    }
  };

  STAGE(0, 0);
  for (int kt = 0; kt < Ksteps; ++kt) {
    const int buf = kt & 1;
    if (kt + 1 < Ksteps) {
      STAGE(buf ^ 1, (kt + 1) * 128);
      if constexpr (LOADS == 8)
        asm volatile("s_waitcnt vmcnt(8)" ::: "memory");
      else if constexpr (LOADS == 6)
        asm volatile("s_waitcnt vmcnt(6)" ::: "memory");
      else
        asm volatile("s_waitcnt vmcnt(4)" ::: "memory");
    } else {
      asm volatile("s_waitcnt vmcnt(0)" ::: "memory");
    }
    __builtin_amdgcn_s_barrier();
    __builtin_amdgcn_sched_barrier(0);
#pragma unroll
    for (int kk = 0; kk < 4; ++kk) {
      const int lo = (((kk * 2 + (qq >> 1)) ^ (rl & 7)) << 1) | (qq & 1);
      long af[MI];
#pragma unroll
      for (int i = 0; i < MI; ++i) af[i] = As[buf][wm + i * 16 + rl][lo];
      long bw[NJ];
#pragma unroll
      for (int j = 0; j < NJ; ++j) bw[j] = Ws[buf][wn + j * 16 + rl][lo];
#pragma unroll
      for (int i = 0; i < MI; ++i)
#pragma unroll
        for (int j = 0; j < NJ; ++j)
          acc[i][j] = __builtin_amdgcn_mfma_f32_16x16x32_fp8_fp8(af[i], bw[j], acc[i][j], 0, 0, 0);
    }
    __builtin_amdgcn_sched_barrier(0);
    __builtin_amdgcn_s_barrier();
  }

  constexpr float S = 0.0625f;  // 1/16 weight descale
  const int rq = qq * 4;
  if constexpr (EPI == 1) {
    const int b = m0 >> 8;
    const float* gm = gmods + (size_t)b * 6144;
#pragma unroll
    for (int j = 0; j < NJ; ++j) {
      const int n = n0 + wn + j * 16 + rl;
      const float g = gm[n];
      const float bv = bias ? bias[n] : 0.f;
#pragma unroll
      for (int i = 0; i < MI; ++i) {
        const int mrow = m0 + wm + i * 16 + rq;
#pragma unroll
        for (int r = 0; r < 4; ++r) {
          float* p = RX + (size_t)(mrow + r) * 1024 + n;
          *p += g * (acc[i][j][r] * S + bv);
        }
      }
    }
  } else if constexpr (EPI == 2) {
    const int region = n0 >> 10;  // 0=q,1=k,2=v
    const int h = ((n0 + wn) >> 6) & 15;
    const int bh = (m0 >> 8) * 16 + h;
    if (region == 2) {
#pragma unroll
      for (int i = 0; i < MI; ++i)
#pragma unroll
        for (int r = 0; r < 4; ++r) {
          const int token = (m0 + wm + i * 16 + rq + r) & 255;
          u16* dst = ob2 + ((size_t)bh * 256 + token) * 64 + rl;
#pragma unroll
          for (int j = 0; j < 4; ++j) dst[j * 16] = f2bf(acc[i][j][r] * S);
        }
    } else {
      const float* nw = region ? nw_k : nw_q;
      u16* obuf = region ? ob1 : ob0;
      float wv[4];
#pragma unroll
      for (int j = 0; j < 4; ++j) wv[j] = nw[j * 16 + rl];
      const float f0 = __powf(10000.f, -(float)(2 * rl) * (1.f / 64.f));
      const float f1 = __powf(10000.f, -(float)(2 * (16 + rl)) * (1.f / 64.f));
#pragma unroll
      for (int i = 0; i < MI; ++i) {
        float va[4][4];
        float ss[4];
#pragma unroll
        for (int r = 0; r < 4; ++r) {
          ss[r] = 0.f;
#pragma unroll
          for (int j = 0; j < 4; ++j) {
            va[j][r] = acc[i][j][r] * S;
            ss[r] += va[j][r] * va[j][r];
          }
        }
#pragma unroll
        for (int off = 1; off < 16; off <<= 1)
#pragma unroll
          for (int r = 0; r < 4; ++r) ss[r] += __shfl_xor(ss[r], off, 64);
#pragma unroll
        for (int r = 0; r < 4; ++r) {
          const int token = (m0 + wm + i * 16 + rq + r) & 255;
          const float rms = rsqrtf(ss[r] * (1.f / 64.f) + 1e-6f);
          float nv[4];
#pragma unroll
          for (int j = 0; j < 4; ++j) nv[j] = va[j][r] * rms * wv[j];
          float s0, c0, s1, c1;
          __sincosf((float)token * f0, &s0, &c0);
          __sincosf((float)token * f1, &s1, &c1);
          u16* dst = obuf + ((size_t)bh * 256 + token) * 64 + rl;
          dst[0]  = f2bf(nv[0] * c0 - nv[2] * s0);
          dst[16] = f2bf(nv[1] * c1 - nv[3] * s1);
          dst[32] = f2bf(nv[2] * c0 + nv[0] * s0);
          dst[48] = f2bf(nv[3] * c1 + nv[1] * s1);
        }
      }
    }
  } else if constexpr (EPI == 3) {
    const int ubase = ((n0 + wn) >> 1) + rl;
#pragma unroll
    for (int i = 0; i < MI; ++i)
#pragma unroll
      for (int r = 0; r < 4; ++r) {
        const int row = m0 + wm + i * 16 + rq + r;
        u8* dst = h1o + (size_t)row * 2816 + ubase;
#pragma unroll
        for (int p = 0; p < 2; ++p) {
          const float a = acc[i][2 * p][r] * S;
          const float b3 = acc[i][2 * p + 1][r] * S;
          dst[p * 16] = (u8)f2f8(silu_f(a) * b3);
        }
      }
  }
}

// ---------------------------------------------------------------------------
// Merged weight conversion v5: v4 structure + non-temporal loads/stores
// (read-once f32 weights, write-once fp8 out -> bypass L2 allocation).
// Grid 13696: [0,3072) qkv | [3072,4096) proj | [4096,9600) w13 | rest w2.
// ---------------------------------------------------------------------------
__global__ __launch_bounds__(256) void conv_all_kernel(
    const float* __restrict__ qkvw, const float* __restrict__ projw,
    const float* __restrict__ w1, const float* __restrict__ w3,
    const float* __restrict__ w2, u8* __restrict__ WB)
{
  __shared__ u32 lbuf[1024];
  const int bid = blockIdx.x;
  const int tid = threadIdx.x;
  if (bid < 4096) {
    const float* src;
    u8* dstbase;
    if (bid < 3072) {
      const int d = bid / 768, rb = bid - d * 768;
      src = qkvw + (size_t)d * 3145728 + (size_t)rb * 4096;
      dstbase = WB + (size_t)d * 12713984 + (size_t)rb * 4096;
    } else {
      const int d = (bid - 3072) >> 8, rb = (bid - 3072) & 255;
      src = projw + (size_t)d * 1048576 + (size_t)rb * 4096;
      dstbase = WB + (size_t)d * 12713984 + 3145728 + (size_t)rb * 4096;
    }
    f32x4 v[4];
#pragma unroll
    for (int k = 0; k < 4; ++k)
      v[k] = ldnt4(src + (k * 256 + tid) * 4);
#pragma unroll
    for (int k = 0; k < 4; ++k)
      lbuf[k * 256 + tid] = pk4f8(v[k].x * 16.f, v[k].y * 16.f, v[k].z * 16.f, v[k].w * 16.f);
    __syncthreads();
    stnt4(dstbase + tid * 16, *(u32x4*)&lbuf[tid * 4]);
  } else if (bid < 9600) {
    const int base = (bid - 4096) * 4 + (tid >> 6);
    const int d = base / 5504, rW = base % 5504;
    const int t = rW >> 5, s = rW & 31;
    const int unit = 16 * t + (s & 15);
    const int lane = tid & 63;
    const int lrow = tid >> 6;
    if (unit < 2730) {
      const float* src = ((s < 16) ? w1 : w3) + (size_t)d * 2795520 + (size_t)unit * 1024;
      f32x4 v[4];
#pragma unroll
      for (int rep = 0; rep < 4; ++rep)
        v[rep] = ldnt4(src + rep * 256 + lane * 4);
#pragma unroll
      for (int rep = 0; rep < 4; ++rep)
        lbuf[lrow * 256 + rep * 64 + lane] =
            pk4f8(v[rep].x * 16.f, v[rep].y * 16.f, v[rep].z * 16.f, v[rep].w * 16.f);
    } else {
#pragma unroll
      for (int rep = 0; rep < 4; ++rep)
        lbuf[lrow * 256 + rep * 64 + lane] = 0;
    }
    __syncthreads();
    u8* dst = WB + (size_t)d * 12713984 + 4194304 + (size_t)rW * 1024 + lane * 16;
    stnt4(dst, *(u32x4*)&lbuf[lrow * 256 + lane * 4]);
  } else {
    const int rc = bid - 9600;
    const int d = rc >> 10, r = rc & 1023;
    const float* src = w2 + (size_t)d * 2795520 + (size_t)r * 2730;
    u8* dst = WB + (size_t)d * 12713984 + 9830400 + (size_t)r * 2816;
    u32 o[3];
#pragma unroll
    for (int it = 0; it < 3; ++it) {
      const int c = tid * 4 + it * 1024;
      if (c + 4 <= 2730) {
        f32x4 vv = ldnt4(src + c);  // rows 4B-aligned; dwordx4 ok
        o[it] = pk4f8(vv.x * 16.f, vv.y * 16.f, vv.z * 16.f, vv.w * 16.f);
      } else {
        float v[4];
#pragma unroll
        for (int i = 0; i < 4; ++i)
          v[i] = (c + i < 2730) ? src[c + i] * 16.f : 0.f;
        o[it] = pk4f8(v[0], v[1], v[2], v[3]);
      }
    }
#pragma unroll
    for (int it = 0; it < 3; ++it) {
      const int c = tid * 4 + it * 1024;
      if (c < 2816) lbuf[c >> 2] = o[it];
    }
    __syncthreads();
    if (tid < 176)
      stnt4(dst + tid * 16, *(u32x4*)&lbuf[tid * 4]);
  }
}

// zero h1 pad cols [2752,2816)
__global__ __launch_bounds__(256) void zt_kernel(u8* __restrict__ h1) {
  const int idx = blockIdx.x * 256 + threadIdx.x;  // 32768
  const int row = idx >> 4, c = idx & 15;
  *(u32*)(h1 + (size_t)row * 2816 + 2752 + c * 4) = 0;
}

// ---------------------------------------------------------------------------
// Conditioning
// ---------------------------------------------------------------------------
__global__ __launch_bounds__(64) void cond_kernel(
    const float* __restrict__ cfg_s, const float* __restrict__ w1,
    const float* __restrict__ b1, const float* __restrict__ w2,
    const float* __restrict__ b2, const float* __restrict__ ce,
    const int* __restrict__ y, float* __restrict__ sc)
{
  const int j = blockIdx.x, b = blockIdx.y, lane = threadIdx.x;
  const float s = cfg_s[b];
  const float4* wr = (const float4*)(w2 + (size_t)j * 1024);
  const float4* w1r = (const float4*)w1;
  const float4* b1r = (const float4*)b1;
  float acc = 0.f;
#pragma unroll
  for (int rep = 0; rep < 4; ++rep) {
    const int c = rep * 64 + lane;
    float4 w = wr[c];
    float4 a = w1r[c];
    float4 bb = b1r[c];
    acc += w.x * silu_f(s * a.x + bb.x) + w.y * silu_f(s * a.y + bb.y) +
           w.z * silu_f(s * a.z + bb.z) + w.w * silu_f(s * a.w + bb.w);
  }
  acc = waveAllSum(acc);
  if (lane == 0) {
    float v = ce[(size_t)y[b] * 1024 + j] + acc + b2[j];
    sc[(size_t)b * 1024 + j] = silu_f(v);
  }
}

// ada + final modulations in one dispatch: grid 1664 blocks x 256 thr.
// Weight rows read non-temporally (read-once); sc slice cached in registers.
__global__ __launch_bounds__(256, 2) void modlin_ada_kernel(
    const float* __restrict__ adaw, const float* __restrict__ adab,
    const float* __restrict__ finw, const float* __restrict__ finb,
    const float* __restrict__ sc, float* __restrict__ mods,
    float* __restrict__ fmods)
{
  const int tid = threadIdx.x;
  const int lane = tid & 63;
  const int wave = tid >> 6;
  const int j0 = blockIdx.x * 16 + wave * 4;
  f32x4 sreg[4][8];
#pragma unroll
  for (int rep = 0; rep < 4; ++rep)
#pragma unroll
    for (int b = 0; b < 8; ++b)
      sreg[rep][b] = *(const f32x4*)(sc + (size_t)b * 1024 + rep * 256 + lane * 4);
  const bool fin = j0 >= 24576;
  const int jrel = fin ? (j0 - 24576) : j0;
  const float* Wb = fin ? finw : adaw;
  const float* Bb = fin ? finb : adab;
#pragma unroll
  for (int r = 0; r < 4; ++r) {
    const int j = jrel + r;
    const float* wr = Wb + (size_t)j * 1024;
    float acc[8];
#pragma unroll
    for (int b = 0; b < 8; ++b) acc[b] = 0.f;
#pragma unroll
    for (int rep = 0; rep < 4; ++rep) {
      f32x4 wv = ldnt4(wr + (rep * 64 + lane) * 4);
#pragma unroll
      for (int b = 0; b < 8; ++b) {
        f32x4 s4 = sreg[rep][b];
        acc[b] += wv.x * s4.x + wv.y * s4.y + wv.z * s4.z + wv.w * s4.w;
      }
    }
#pragma unroll
    for (int b = 0; b < 8; ++b) acc[b] = waveAllSum(acc[b]);
    if (lane == 0) {
      const float bb = Bb[j];
      if (fin) {
#pragma unroll
        for (int b = 0; b < 8; ++b) fmods[(size_t)b * 2048 + j] = acc[b] + bb;
      } else {
        const int d = j / 6144;
        const int jj = j - d * 6144;
        float* outb = mods + (size_t)d * 49152;
#pragma unroll
        for (int b = 0; b < 8; ++b) outb[(size_t)b * 6144 + jj] = acc[b] + bb;
      }
    }
  }
}

// ---------------------------------------------------------------------------
// Patch embed
// ---------------------------------------------------------------------------
__global__ __launch_bounds__(256) void patch_kernel(
    const float* __restrict__ x, const float* __restrict__ pw,
    const float* __restrict__ pb, const float* __restrict__ pos,
    float* __restrict__ xc)
{
  const int n = blockIdx.x, b = blockIdx.y, tid = threadIdx.x;
  __shared__ float pv[16];
  if (tid < 16) {
    const int ci = tid >> 2, pi = (tid >> 1) & 1, pj = tid & 1;
    const int i = n >> 4, j = n & 15;
    pv[tid] = x[((size_t)(b * 4 + ci) * 32 + i * 2 + pi) * 32 + j * 2 + pj];
  }
  __syncthreads();
#pragma unroll
  for (int qq = 0; qq < 4; ++qq) {
    const int c = qq * 256 + tid;
    const float4* wr = (const float4*)(pw + (size_t)c * 16);
    float acc = pb[c] + pos[(size_t)n * 1024 + c];
#pragma unroll
    for (int g = 0; g < 4; ++g) {
      float4 w = wr[g];
      acc += w.x * pv[g * 4] + w.y * pv[g * 4 + 1] + w.z * pv[g * 4 + 2] + w.w * pv[g * 4 + 3];
    }
    xc[((size_t)b * 256 + n) * 1024 + c] = acc;
  }
}

// ---------------------------------------------------------------------------
// RMSNorm + adaLN modulate -> fp8 (block per row, coalesced tid*4)
// ---------------------------------------------------------------------------
__global__ __launch_bounds__(256) void normmod8_kernel(
    const float* __restrict__ xc, const float* __restrict__ w,
    const float* __restrict__ mods, int mult_off, int shift_off,
    u8* __restrict__ out)
{
  const int m = blockIdx.x, b = m >> 8, tid = threadIdx.x;
  const float* row = xc + (size_t)m * 1024;
  float4 v = *(const float4*)(row + tid * 4);
  float ss = v.x * v.x + v.y * v.y + v.z * v.z + v.w * v.w;
  ss = waveAllSum(ss);
  __shared__ float red[4];
  if ((tid & 63) == 0) red[tid >> 6] = ss;
  __syncthreads();
  const float tot = red[0] + red[1] + red[2] + red[3];
  const float r = rsqrtf(tot * (1.f / 1024.f) + 1e-6f);
  const float* mb = mods + (size_t)b * 6144;
  const int c = tid * 4;
  float4 wv = *(const float4*)(w + c);
  float4 mu = *(const float4*)(mb + mult_off + c);
  float4 sh = *(const float4*)(mb + shift_off + c);
  u32 p = pk4f8(v.x * r * wv.x * (1.f + mu.x) + sh.x,
                v.y * r * wv.y * (1.f + mu.y) + sh.y,
                v.z * r * wv.z * (1.f + mu.z) + sh.z,
                v.w * r * wv.w * (1.f + mu.w) + sh.w);
  *(u32*)(out + (size_t)m * 1024 + c) = p;
}

// ---------------------------------------------------------------------------
// MFMA attention (bf16 q/k/v in, fp8 out at o[b,n,h,d])
// ---------------------------------------------------------------------------
__global__ __launch_bounds__(256) void attn_kernel(
    const u16* __restrict__ qb, const u16* __restrict__ kb,
    const u16* __restrict__ vb, u8* __restrict__ o)
{
  __shared__ alignas(16) u16 Kt[128][72];
  __shared__ alignas(16) u16 Vtt[64][136];
  __shared__ alignas(16) u16 Pw[4][16][136];
  const int bh = blockIdx.x;
  const int qbase = blockIdx.y * 64;
  const int tid = threadIdx.x;
  const int lane = tid & 63;
  const int wave = tid >> 6;
  const int rl = lane & 15;
  const int kq = (lane >> 4) * 8;
  const int rowg = (lane >> 4) * 4;

  const int q0 = qbase + wave * 16;
  const u16* qsrc = qb + ((size_t)bh * 256 + q0 + rl) * 64 + kq;
  const bf16x8 a0 = *(const bf16x8*)(qsrc);
  const bf16x8 a1 = *(const bf16x8*)(qsrc + 32);

  float m[4], l[4];
  f32x4 oacc[4];
#pragma unroll
  for (int r = 0; r < 4; ++r) { m[r] = -1e30f; l[r] = 0.f; }
#pragma unroll
  for (int dt = 0; dt < 4; ++dt) oacc[dt] = (f32x4){0.f, 0.f, 0.f, 0.f};

  for (int kt = 0; kt < 2; ++kt) {
    __syncthreads();
#pragma unroll
    for (int c = 0; c < 4; ++c) {
      const int flat = c * 256 + tid;
      const int row = flat >> 3;
      const int col = (flat & 7) * 8;
      uint4 v = *(const uint4*)(kb + ((size_t)bh * 256 + kt * 128 + row) * 64 + col);
      *(uint4*)&Kt[row][col] = v;
    }
    {
      const int tt = tid & 63;
      const int dh = tid >> 6;
      const int r0 = tt * 2;
      const u16* s0 = vb + ((size_t)bh * 256 + kt * 128 + r0) * 64 + dh * 16;
      const u16* s1 = s0 + 64;
#pragma unroll
      for (int g = 0; g < 2; ++g) {
        uint4 A = *(const uint4*)(s0 + g * 8);
        uint4 B = *(const uint4*)(s1 + g * 8);
        const u32 aw[4] = {A.x, A.y, A.z, A.w};
        const u32 bw[4] = {B.x, B.y, B.z, B.w};
#pragma unroll
        for (int q = 0; q < 4; ++q) {
          const int d2 = dh * 16 + g * 8 + q * 2;
          const u32 lo = (aw[q] & 0xffffu) | (bw[q] << 16);
          const u32 hi = (aw[q] >> 16) | (bw[q] & 0xffff0000u);
          *(u32*)&Vtt[d2][r0] = lo;
          *(u32*)&Vtt[d2 + 1][r0] = hi;
        }
      }
    }
    __syncthreads();

    f32x4 sacc[8];
#pragma unroll
    for (int t = 0; t < 8; ++t) sacc[t] = (f32x4){0.f, 0.f, 0.f, 0.f};
#pragma unroll
    for (int t = 0; t < 8; ++t) {
      bf16x8 k0 = *(const bf16x8*)&Kt[t * 16 + rl][kq];
      bf16x8 k1 = *(const bf16x8*)&Kt[t * 16 + rl][32 + kq];
      sacc[t] = __builtin_amdgcn_mfma_f32_16x16x32_bf16(a0, k0, sacc[t], 0, 0, 0);
      sacc[t] = __builtin_amdgcn_mfma_f32_16x16x32_bf16(a1, k1, sacc[t], 0, 0, 0);
    }
    float cmax[4];
#pragma unroll
    for (int r = 0; r < 4; ++r) cmax[r] = sacc[0][r];
#pragma unroll
    for (int t = 1; t < 8; ++t)
#pragma unroll
      for (int r = 0; r < 4; ++r) cmax[r] = fmaxf(cmax[r], sacc[t][r]);
#pragma unroll
    for (int off = 1; off < 16; off <<= 1)
#pragma unroll
      for (int r = 0; r < 4; ++r) cmax[r] = fmaxf(cmax[r], __shfl_xor(cmax[r], off, 64));
#pragma unroll
    for (int r = 0; r < 4; ++r) {
      const float mn = fmaxf(m[r], cmax[r]);
      const float corr = __expf((m[r] - mn) * 0.125f);
      l[r] *= corr;
#pragma unroll
      for (int dt = 0; dt < 4; ++dt) oacc[dt][r] *= corr;
      m[r] = mn;
    }
    float lsum[4] = {0.f, 0.f, 0.f, 0.f};
#pragma unroll
    for (int t = 0; t < 8; ++t)
#pragma unroll
      for (int r = 0; r < 4; ++r) {
        const float p = __expf((sacc[t][r] - m[r]) * 0.125f);
        lsum[r] += p;
        Pw[wave][rowg + r][t * 16 + rl] = f2bf(p);
      }
#pragma unroll
    for (int off = 1; off < 16; off <<= 1)
#pragma unroll
      for (int r = 0; r < 4; ++r) lsum[r] += __shfl_xor(lsum[r], off, 64);
#pragma unroll
    for (int r = 0; r < 4; ++r) l[r] += lsum[r];
#pragma unroll
    for (int ks = 0; ks < 4; ++ks) {
      bf16x8 pa = *(const bf16x8*)&Pw[wave][rl][ks * 32 + kq];
#pragma unroll
      for (int dt = 0; dt < 4; ++dt) {
        bf16x8 vf = *(const bf16x8*)&Vtt[dt * 16 + rl][ks * 32 + kq];
        oacc[dt] = __builtin_amdgcn_mfma_f32_16x16x32_bf16(pa, vf, oacc[dt], 0, 0, 0);
      }
    }
  }
  const int b = bh >> 4, h = bh & 15;
#pragma unroll
  for (int r = 0; r < 4; ++r) {
    const float inv = 1.f / l[r];
    const int qrow = q0 + rowg + r;
    u8* dst = o + (((size_t)b * 256 + qrow) * 16 + h) * 64 + rl;
#pragma unroll
    for (int dt = 0; dt < 4; ++dt)
      dst[dt * 16] = (u8)f2f8(oacc[dt][r] * inv);
  }
}

// ---------------------------------------------------------------------------
// Fused final LayerNorm + modulate + final linear + unpatchify.
// ---------------------------------------------------------------------------
__global__ __launch_bounds__(256) void lnfinal_kernel(
    const float* __restrict__ xc, const float* __restrict__ fmods,
    const float* __restrict__ w, const float* __restrict__ bias,
    float* __restrict__ out)
{
  __shared__ alignas(16) u16 xb[16][1024];  // 32KB normalized bf16 rows
  const int tid = threadIdx.x;
  const int lane = tid & 63;
  const int wave = tid >> 6;
  const int mbase = blockIdx.x * 16;
#pragma unroll
  for (int rr = 0; rr < 4; ++rr) {
    const int mloc = wave * 4 + rr;
    const int m = mbase + mloc;
    const int b = m >> 8;
    const float* row = xc + (size_t)m * 1024;
    float4 v[4];
    float s1 = 0.f, s2 = 0.f;
#pragma unroll
    for (int g = 0; g < 4; ++g) {
      v[g] = *(const float4*)(row + g * 256 + lane * 4);
      s1 += v[g].x + v[g].y + v[g].z + v[g].w;
      s2 += v[g].x * v[g].x + v[g].y * v[g].y + v[g].z * v[g].z + v[g].w * v[g].w;
    }
    s1 = waveAllSum(s1);
    s2 = waveAllSum(s2);
    const float mean = s1 * (1.f / 1024.f);
    const float var = s2 * (1.f / 1024.f) - mean * mean;
    const float rstd = rsqrtf(var + 1e-5f);
    const float* mb = fmods + (size_t)b * 2048;
#pragma unroll
    for (int g = 0; g < 4; ++g) {
      const int c = g * 256 + lane * 4;
      float4 sh = *(const float4*)(mb + c);
      float4 sl = *(const float4*)(mb + 1024 + c);
      union { u16 u[4]; uint2 v2; } pk;
      pk.u[0] = f2bf((v[g].x - mean) * rstd * (1.f + sl.x) + sh.x);
      pk.u[1] = f2bf((v[g].y - mean) * rstd * (1.f + sl.y) + sh.y);
      pk.u[2] = f2bf((v[g].z - mean) * rstd * (1.f + sl.z) + sh.z);
      pk.u[3] = f2bf((v[g].w - mean) * rstd * (1.f + sl.w) + sh.w);
      *(uint2*)&xb[mloc][c] = pk.v2;
    }
  }
  __syncthreads();
  const int mloc = tid >> 4;
  const int j = tid & 15;
  const int m = mbase + mloc;
  const float* wr = w + (size_t)j * 1024;
  float acc = 0.f;
  for (int k = 0; k < 1024; k += 8) {
    uint4 xv = *(const uint4*)&xb[mloc][k];
    const u16* xu = (const u16*)&xv;
    float4 w0 = *(const float4*)(wr + k);
    float4 w1 = *(const float4*)(wr + k + 4);
    acc += bf2f(xu[0]) * w0.x + bf2f(xu[1]) * w0.y + bf2f(xu[2]) * w0.z + bf2f(xu[3]) * w0.w;
    acc += bf2f(xu[4]) * w1.x + bf2f(xu[5]) * w1.y + bf2f(xu[6]) * w1.z + bf2f(xu[7]) * w1.w;
  }
  acc += bias[j];
  const int b = m >> 8, n = m & 255;
  const int i = n >> 4, jj = n & 15;
  const int pi = (j >> 3) & 1, pj = (j >> 2) & 1, oc = j & 3;
  out[((size_t)(b * 4 + oc) * 32 + i * 2 + pi) * 32 + jj * 2 + pj] = acc;
}

// ---------------------------------------------------------------------------
extern "C" void kernel_launch(void* const* d_in, const int* in_sizes, int n_in,
                              void* d_out, int out_size, void* d_ws, size_t ws_size,
                              hipStream_t stream) {
  const float* x       = (const float*)d_in[0];
  const int*   y       = (const int*)  d_in[1];
  const float* cfg_s   = (const float*)d_in[2];
  const float* patch_w = (const float*)d_in[3];
  const float* patch_b = (const float*)d_in[4];
  const float* pos_e   = (const float*)d_in[5];
  const float* class_e = (const float*)d_in[6];
  const float* cfg_w1  = (const float*)d_in[7];
  const float* cfg_b1  = (const float*)d_in[8];
  const float* cfg_w2  = (const float*)d_in[9];
  const float* cfg_b2  = (const float*)d_in[10];
  const float* n1w     = (const float*)d_in[11];
  const float* n2w     = (const float*)d_in[12];
  const float* qkvw    = (const float*)d_in[13];
  const float* projw   = (const float*)d_in[14];
  const float* projb   = (const float*)d_in[15];
  const float* qnw     = (const float*)d_in[16];
  const float* knw     = (const float*)d_in[17];
  const float* w1      = (const float*)d_in[18];
  const float* w2      = (const float*)d_in[19];
  const float* w3      = (const float*)d_in[20];
  const float* adaw    = (const float*)d_in[21];
  const float* adab    = (const float*)d_in[22];
  const float* finaw   = (const float*)d_in[23];
  const float* finab   = (const float*)d_in[24];
  const float* flw     = (const float*)d_in[25];
  const float* flb     = (const float*)d_in[26];
  (void)in_sizes; (void)n_in; (void)out_size;

  char* ws = (char*)d_ws;
  const size_t MB = 1024 * 1024;
  if (ws_size < 96 * MB) return;
  float* sc    = (float*)(ws + 32 * 1024);             // 32KB
  float* mods  = (float*)(ws + 64 * 1024);             // 768KB
  float* fmods = (float*)(ws + 64 * 1024 + 786432);    // 64KB
  float* xc    = (float*)(ws + 1 * MB);                // 8MB
  u8*    xm8   = (u8*)   (ws + 9 * MB);                // 2MB
  u16*   qbuf  = (u16*)  (ws + 11 * MB);               // 4MB
  u16*   kbuf  = (u16*)  (ws + 15 * MB);               // 4MB
  u16*   vbuf  = (u16*)  (ws + 19 * MB);               // 4MB
  u8*    h18   = (u8*)   (ws + 23 * MB);               // 5.7MB
  u8*    WB    = (u8*)   (ws + 33 * MB);               // 48.5MB fp8 weights
  const size_t LSTR = 12713984;

  cond_kernel<<<dim3(1024, 8), 64, 0, stream>>>(cfg_s, cfg_w1, cfg_b1, cfg_w2,
                                                cfg_b2, class_e, y, sc);
  modlin_ada_kernel<<<1664, 256, 0, stream>>>(adaw, adab, finaw, finab, sc,
                                              mods, fmods);
  patch_kernel<<<dim3(256, 8), 256, 0, stream>>>(x, patch_w, patch_b, pos_e, xc);
  conv_all_kernel<<<13696, 256, 0, stream>>>(qkvw, projw, w1, w3, w2, WB);
  zt_kernel<<<128, 256, 0, stream>>>(h18);

  for (int d = 0; d < 4; ++d) {
    const float* md = mods + (size_t)d * 49152;
    u8* WL = WB + (size_t)d * LSTR;
    normmod8_kernel<<<2048, 256, 0, stream>>>(xc, n1w + d * 1024, md, 1024, 0, xm8);
    gemm8_t<64, 128, 2><<<768, 256, 0, stream>>>(xm8, 1024, WL, 1024, 8, 32,
                                                 nullptr, nullptr, nullptr,
                                                 qbuf, kbuf, vbuf, nullptr,
                                                 qnw + d * 64, knw + d * 64);
    attn_kernel<<<dim3(128, 4), 256, 0, stream>>>(qbuf, kbuf, vbuf, xm8);
    gemm8_t<64, 64, 1><<<512, 256, 0, stream>>>(xm8, 1024, WL + 3145728, 1024, 8, 32,
                                                xc, md + 2048, projb + d * 1024,
                                                nullptr, nullptr, nullptr, nullptr,
                                                nullptr, nullptr);
    normmod8_kernel<<<2048, 256, 0, stream>>>(xc, n2w + d * 1024, md, 4096, 3072, xm8);
    gemm8_t<64, 128, 3><<<1376, 256, 0, stream>>>(xm8, 1024, WL + 4194304, 1024, 8, 32,
                                                  nullptr, nullptr, nullptr,
                                                  nullptr, nullptr, nullptr, h18,
                                                  nullptr, nullptr);
    gemm8_t<64, 64, 1><<<512, 256, 0, stream>>>(h18, 2816, WL + 9830400, 2816, 22, 32,
                                                xc, md + 5120, nullptr,
                                                nullptr, nullptr, nullptr, nullptr,
                                                nullptr, nullptr);
  }

  lnfinal_kernel<<<128, 256, 0, stream>>>(xc, fmods, flw, flb, (float*)d_out);
}

// Round 16
// 533.341 us; speedup vs baseline: 1.0701x; 1.0701x over previous
//
#include <hip/hip_runtime.h>

typedef unsigned char u8;
typedef unsigned short u16;
typedef unsigned int u32;
typedef float f32x4 __attribute__((ext_vector_type(4)));
typedef u32 u32x4 __attribute__((ext_vector_type(4)));
typedef __bf16 bf16x8 __attribute__((ext_vector_type(8)));

#define DEV __device__ __forceinline__

DEV u16 f2bf(float f) {
  u32 u = __builtin_bit_cast(u32, f);
  u += 0x7fffu + ((u >> 16) & 1u);
  return (u16)(u >> 16);
}
DEV float bf2f(u16 u) { return __builtin_bit_cast(float, (u32)u << 16); }

// f32 -> OCP e4m3fn: hardware cvt_pk when available, software RNE fallback
#if __has_builtin(__builtin_amdgcn_cvt_pk_fp8_f32)
DEV u32 pk4f8(float x, float y, float z, float w) {
  int v = 0;
  v = __builtin_amdgcn_cvt_pk_fp8_f32(x, y, v, false);
  v = __builtin_amdgcn_cvt_pk_fp8_f32(z, w, v, true);
  return (u32)v;
}
DEV u32 f2f8(float f) {
  return (u32)(__builtin_amdgcn_cvt_pk_fp8_f32(f, f, 0, false) & 0xff);
}
#else
DEV u32 f2f8(float f) {
  u32 u = __builtin_bit_cast(u32, f);
  u32 s = (u >> 31) << 7;
  float a = __builtin_fabsf(f);
  if (a >= 448.f) return s | 0x7Eu;
  if (a < 0.015625f) {
    int m = (int)(a * 512.f + 0.5f);
    return s | (u32)m;
  }
  u32 b = __builtin_bit_cast(u32, a);
  b += 0x7FFFFu + ((b >> 20) & 1u);
  u32 E = (b >> 23) - 120u;
  if (E > 15u) return s | 0x7Eu;
  return s | (E << 3) | ((b >> 20) & 7u);
}
DEV u32 pk4f8(float x, float y, float z, float w) {
  return f2f8(x) | (f2f8(y) << 8) | (f2f8(z) << 16) | (f2f8(w) << 24);
}
#endif

// non-temporal LOADS only (read-once f32 weights). Stores stay cached: the
// fp8 WB buffer is re-read by every GEMM and must live in L3.
DEV f32x4 ldnt4(const float* p) {
  return __builtin_nontemporal_load((const f32x4*)p);
}

DEV float waveAllSum(float x) {
#pragma unroll
  for (int off = 32; off > 0; off >>= 1) x += __shfl_xor(x, off, 64);
  return x;
}
DEV float silu_f(float x) { return x / (1.f + __expf(-x)); }

DEV void gll16(const void* g, void* l) {
  __builtin_amdgcn_global_load_lds(
      (const __attribute__((address_space(1))) void*)g,
      (__attribute__((address_space(3))) void*)l, 16, 0, 0);
}

// ---------------------------------------------------------------------------
// FP8 GEMM: C = A_fp8[m,k] * (16*W)_fp8[n,k]^T * (1/16); BM x BN tile,
// BK=128, 4 waves (2x2), dbuf global_load_lds + counted vmcnt.
// LDS rows 128B as long[16]; 16B-chunk XOR swizzle by row&7 on global SOURCE
// (linear LDS dest, rule #21) and on the ds_read index.
// EPI: 1 = residual RX += gm*(acc*S+bias); 2 = qk-RMSNorm+RoPE+v -> bf16
// q/k/v; 3 = SwiGLU pair-fuse -> h1 fp8 (w1/w3 interleaved 16-unit groups).
// ---------------------------------------------------------------------------
template<int BM, int BN, int EPI>
__global__ __launch_bounds__(256, (BM == 128 ? 2 : ((BM + BN) == 128 ? 4 : 3)))
void gemm8_t(
    const u8* __restrict__ A, int lda,
    const u8* __restrict__ W, int ldw,
    int Ksteps, int nbx,
    float* __restrict__ RX, const float* __restrict__ gmods,
    const float* __restrict__ bias,
    u16* __restrict__ ob0, u16* __restrict__ ob1, u16* __restrict__ ob2,
    u8* __restrict__ h1o,
    const float* __restrict__ nw_q, const float* __restrict__ nw_k)
{
  constexpr int MI = BM / 32;           // 16-row acc tiles per wave
  constexpr int NJ = BN / 32;           // 16-col acc tiles per wave
  constexpr int LOADS = (BM + BN) / 32; // gll16 per lane per stage
  __shared__ long As[2][BM][16];
  __shared__ long Ws[2][BN][16];
  const int tid = threadIdx.x;
  const int lane = tid & 63;
  const int wave = tid >> 6;
  const int nwg = gridDim.x;
  const int cpx = nwg >> 3;
  const int fb = blockIdx.x;
  const int idx = (fb & 7) * cpx + (fb >> 3);
  const int m0 = (idx % nbx) * BM;
  const int n0 = (idx / nbx) * BN;
  const int wm = (wave >> 1) * (BM / 2);
  const int wn = (wave & 1) * (BN / 2);
  const int rl = lane & 15;
  const int qq = lane >> 4;            // 0..3
  const u8* Abase = A + (size_t)m0 * lda;
  const u8* Wbase = W + (size_t)n0 * ldw;

  f32x4 acc[MI][NJ];
#pragma unroll
  for (int i = 0; i < MI; ++i)
#pragma unroll
    for (int j = 0; j < NJ; ++j) acc[i][j] = (f32x4){0.f, 0.f, 0.f, 0.f};

  auto STAGE = [&](int buf, int k0) {
#pragma unroll
    for (int c = 0; c < BM / 32; ++c) {
      const int flat = c * 256 + tid;
      const int row = flat >> 3;
      const int ch = flat & 7;
      gll16(Abase + (size_t)row * lda + k0 + ((ch ^ (row & 7)) << 4),
            &As[buf][row][ch * 2]);
    }
#pragma unroll
    for (int c = 0; c < BN / 32; ++c) {
      const int flat = c * 256 + tid;
      const int row = flat >> 3;
      const int ch = flat & 7;
      gll16(Wbase + (size_t)row * ldw + k0 + ((ch ^ (row & 7)) << 4),
            &Ws[buf][row][ch * 2]);
    }
  };

  STAGE(0, 0);
  for (int kt = 0; kt < Ksteps; ++kt) {
    const int buf = kt & 1;
    if (kt + 1 < Ksteps) {
      STAGE(buf ^ 1, (kt + 1) * 128);
      if constexpr (LOADS == 8)
        asm volatile("s_waitcnt vmcnt(8)" ::: "memory");
      else if constexpr (LOADS == 6)
        asm volatile("s_waitcnt vmcnt(6)" ::: "memory");
      else
        asm volatile("s_waitcnt vmcnt(4)" ::: "memory");
    } else {
      asm volatile("s_waitcnt vmcnt(0)" ::: "memory");
    }
    __builtin_amdgcn_s_barrier();
    __builtin_amdgcn_sched_barrier(0);
#pragma unroll
    for (int kk = 0; kk < 4; ++kk) {
      const int lo = (((kk * 2 + (qq >> 1)) ^ (rl & 7)) << 1) | (qq & 1);
      long af[MI];
#pragma unroll
      for (int i = 0; i < MI; ++i) af[i] = As[buf][wm + i * 16 + rl][lo];
      long bw[NJ];
#pragma unroll
      for (int j = 0; j < NJ; ++j) bw[j] = Ws[buf][wn + j * 16 + rl][lo];
#pragma unroll
      for (int i = 0; i < MI; ++i)
#pragma unroll
        for (int j = 0; j < NJ; ++j)
          acc[i][j] = __builtin_amdgcn_mfma_f32_16x16x32_fp8_fp8(af[i], bw[j], acc[i][j], 0, 0, 0);
    }
    __builtin_amdgcn_sched_barrier(0);
    __builtin_amdgcn_s_barrier();
  }

  constexpr float S = 0.0625f;  // 1/16 weight descale
  const int rq = qq * 4;
  if constexpr (EPI == 1) {
    const int b = m0 >> 8;
    const float* gm = gmods + (size_t)b * 6144;
#pragma unroll
    for (int j = 0; j < NJ; ++j) {
      const int n = n0 + wn + j * 16 + rl;
      const float g = gm[n];
      const float bv = bias ? bias[n] : 0.f;
#pragma unroll
      for (int i = 0; i < MI; ++i) {
        const int mrow = m0 + wm + i * 16 + rq;
#pragma unroll
        for (int r = 0; r < 4; ++r) {
          float* p = RX + (size_t)(mrow + r) * 1024 + n;
          *p += g * (acc[i][j][r] * S + bv);
        }
      }
    }
  } else if constexpr (EPI == 2) {
    const int region = n0 >> 10;  // 0=q,1=k,2=v
    const int h = ((n0 + wn) >> 6) & 15;
    const int bh = (m0 >> 8) * 16 + h;
    if (region == 2) {
#pragma unroll
      for (int i = 0; i < MI; ++i)
#pragma unroll
        for (int r = 0; r < 4; ++r) {
          const int token = (m0 + wm + i * 16 + rq + r) & 255;
          u16* dst = ob2 + ((size_t)bh * 256 + token) * 64 + rl;
#pragma unroll
          for (int j = 0; j < 4; ++j) dst[j * 16] = f2bf(acc[i][j][r] * S);
        }
    } else {
      const float* nw = region ? nw_k : nw_q;
      u16* obuf = region ? ob1 : ob0;
      float wv[4];
#pragma unroll
      for (int j = 0; j < 4; ++j) wv[j] = nw[j * 16 + rl];
      const float f0 = __powf(10000.f, -(float)(2 * rl) * (1.f / 64.f));
      const float f1 = __powf(10000.f, -(float)(2 * (16 + rl)) * (1.f / 64.f));
#pragma unroll
      for (int i = 0; i < MI; ++i) {
        float va[4][4];
        float ss[4];
#pragma unroll
        for (int r = 0; r < 4; ++r) {
          ss[r] = 0.f;
#pragma unroll
          for (int j = 0; j < 4; ++j) {
            va[j][r] = acc[i][j][r] * S;
            ss[r] += va[j][r] * va[j][r];
          }
        }
#pragma unroll
        for (int off = 1; off < 16; off <<= 1)
#pragma unroll
          for (int r = 0; r < 4; ++r) ss[r] += __shfl_xor(ss[r], off, 64);
#pragma unroll
        for (int r = 0; r < 4; ++r) {
          const int token = (m0 + wm + i * 16 + rq + r) & 255;
          const float rms = rsqrtf(ss[r] * (1.f / 64.f) + 1e-6f);
          float nv[4];
#pragma unroll
          for (int j = 0; j < 4; ++j) nv[j] = va[j][r] * rms * wv[j];
          float s0, c0, s1, c1;
          __sincosf((float)token * f0, &s0, &c0);
          __sincosf((float)token * f1, &s1, &c1);
          u16* dst = obuf + ((size_t)bh * 256 + token) * 64 + rl;
          dst[0]  = f2bf(nv[0] * c0 - nv[2] * s0);
          dst[16] = f2bf(nv[1] * c1 - nv[3] * s1);
          dst[32] = f2bf(nv[2] * c0 + nv[0] * s0);
          dst[48] = f2bf(nv[3] * c1 + nv[1] * s1);
        }
      }
    }
  } else if constexpr (EPI == 3) {
    const int ubase = ((n0 + wn) >> 1) + rl;
#pragma unroll
    for (int i = 0; i < MI; ++i)
#pragma unroll
      for (int r = 0; r < 4; ++r) {
        const int row = m0 + wm + i * 16 + rq + r;
        u8* dst = h1o + (size_t)row * 2816 + ubase;
#pragma unroll
        for (int p = 0; p < 2; ++p) {
          const float a = acc[i][2 * p][r] * S;
          const float b3 = acc[i][2 * p + 1][r] * S;
          dst[p * 16] = (u8)f2f8(silu_f(a) * b3);
        }
      }
  }
}

// ---------------------------------------------------------------------------
// Merged weight conversion v6: non-temporal f32 loads (read-once) + CACHED
// LDS-packed uint4 stores (WB is re-read by GEMMs -> must stay in L3).
// Grid 13696: [0,3072) qkv | [3072,4096) proj | [4096,9600) w13 | rest w2.
// ---------------------------------------------------------------------------
__global__ __launch_bounds__(256) void conv_all_kernel(
    const float* __restrict__ qkvw, const float* __restrict__ projw,
    const float* __restrict__ w1, const float* __restrict__ w3,
    const float* __restrict__ w2, u8* __restrict__ WB)
{
  __shared__ u32 lbuf[1024];
  const int bid = blockIdx.x;
  const int tid = threadIdx.x;
  if (bid < 4096) {
    const float* src;
    u8* dstbase;
    if (bid < 3072) {
      const int d = bid / 768, rb = bid - d * 768;
      src = qkvw + (size_t)d * 3145728 + (size_t)rb * 4096;
      dstbase = WB + (size_t)d * 12713984 + (size_t)rb * 4096;
    } else {
      const int d = (bid - 3072) >> 8, rb = (bid - 3072) & 255;
      src = projw + (size_t)d * 1048576 + (size_t)rb * 4096;
      dstbase = WB + (size_t)d * 12713984 + 3145728 + (size_t)rb * 4096;
    }
    f32x4 v[4];
#pragma unroll
    for (int k = 0; k < 4; ++k)
      v[k] = ldnt4(src + (k * 256 + tid) * 4);
#pragma unroll
    for (int k = 0; k < 4; ++k)
      lbuf[k * 256 + tid] = pk4f8(v[k].x * 16.f, v[k].y * 16.f, v[k].z * 16.f, v[k].w * 16.f);
    __syncthreads();
    *(u32x4*)(dstbase + tid * 16) = *(u32x4*)&lbuf[tid * 4];
  } else if (bid < 9600) {
    const int base = (bid - 4096) * 4 + (tid >> 6);
    const int d = base / 5504, rW = base % 5504;
    const int t = rW >> 5, s = rW & 31;
    const int unit = 16 * t + (s & 15);
    const int lane = tid & 63;
    const int lrow = tid >> 6;
    if (unit < 2730) {
      const float* src = ((s < 16) ? w1 : w3) + (size_t)d * 2795520 + (size_t)unit * 1024;
      f32x4 v[4];
#pragma unroll
      for (int rep = 0; rep < 4; ++rep)
        v[rep] = ldnt4(src + rep * 256 + lane * 4);
#pragma unroll
      for (int rep = 0; rep < 4; ++rep)
        lbuf[lrow * 256 + rep * 64 + lane] =
            pk4f8(v[rep].x * 16.f, v[rep].y * 16.f, v[rep].z * 16.f, v[rep].w * 16.f);
    } else {
#pragma unroll
      for (int rep = 0; rep < 4; ++rep)
        lbuf[lrow * 256 + rep * 64 + lane] = 0;
    }
    __syncthreads();
    u8* dst = WB + (size_t)d * 12713984 + 4194304 + (size_t)rW * 1024 + lane * 16;
    *(u32x4*)dst = *(u32x4*)&lbuf[lrow * 256 + lane * 4];
  } else {
    const int rc = bid - 9600;
    const int d = rc >> 10, r = rc & 1023;
    const float* src = w2 + (size_t)d * 2795520 + (size_t)r * 2730;
    u8* dst = WB + (size_t)d * 12713984 + 9830400 + (size_t)r * 2816;
    u32 o[3];
#pragma unroll
    for (int it = 0; it < 3; ++it) {
      const int c = tid * 4 + it * 1024;
      if (c + 4 <= 2730) {
        f32x4 vv = ldnt4(src + c);  // rows 4B-aligned; dwordx4 ok
        o[it] = pk4f8(vv.x * 16.f, vv.y * 16.f, vv.z * 16.f, vv.w * 16.f);
      } else {
        float v[4];
#pragma unroll
        for (int i = 0; i < 4; ++i)
          v[i] = (c + i < 2730) ? src[c + i] * 16.f : 0.f;
        o[it] = pk4f8(v[0], v[1], v[2], v[3]);
      }
    }
#pragma unroll
    for (int it = 0; it < 3; ++it) {
      const int c = tid * 4 + it * 1024;
      if (c < 2816) lbuf[c >> 2] = o[it];
    }
    __syncthreads();
    if (tid < 176)
      *(u32x4*)(dst + tid * 16) = *(u32x4*)&lbuf[tid * 4];
  }
}

// zero h1 pad cols [2752,2816)
__global__ __launch_bounds__(256) void zt_kernel(u8* __restrict__ h1) {
  const int idx = blockIdx.x * 256 + threadIdx.x;  // 32768
  const int row = idx >> 4, c = idx & 15;
  *(u32*)(h1 + (size_t)row * 2816 + 2752 + c * 4) = 0;
}

// ---------------------------------------------------------------------------
// Conditioning
// ---------------------------------------------------------------------------
__global__ __launch_bounds__(64) void cond_kernel(
    const float* __restrict__ cfg_s, const float* __restrict__ w1,
    const float* __restrict__ b1, const float* __restrict__ w2,
    const float* __restrict__ b2, const float* __restrict__ ce,
    const int* __restrict__ y, float* __restrict__ sc)
{
  const int j = blockIdx.x, b = blockIdx.y, lane = threadIdx.x;
  const float s = cfg_s[b];
  const float4* wr = (const float4*)(w2 + (size_t)j * 1024);
  const float4* w1r = (const float4*)w1;
  const float4* b1r = (const float4*)b1;
  float acc = 0.f;
#pragma unroll
  for (int rep = 0; rep < 4; ++rep) {
    const int c = rep * 64 + lane;
    float4 w = wr[c];
    float4 a = w1r[c];
    float4 bb = b1r[c];
    acc += w.x * silu_f(s * a.x + bb.x) + w.y * silu_f(s * a.y + bb.y) +
           w.z * silu_f(s * a.z + bb.z) + w.w * silu_f(s * a.w + bb.w);
  }
  acc = waveAllSum(acc);
  if (lane == 0) {
    float v = ce[(size_t)y[b] * 1024 + j] + acc + b2[j];
    sc[(size_t)b * 1024 + j] = silu_f(v);
  }
}

// ada + final modulations in one dispatch: grid 1664 blocks x 256 thr.
// Weight rows read non-temporally (read-once); sc slice cached in registers.
__global__ __launch_bounds__(256, 2) void modlin_ada_kernel(
    const float* __restrict__ adaw, const float* __restrict__ adab,
    const float* __restrict__ finw, const float* __restrict__ finb,
    const float* __restrict__ sc, float* __restrict__ mods,
    float* __restrict__ fmods)
{
  const int tid = threadIdx.x;
  const int lane = tid & 63;
  const int wave = tid >> 6;
  const int j0 = blockIdx.x * 16 + wave * 4;
  f32x4 sreg[4][8];
#pragma unroll
  for (int rep = 0; rep < 4; ++rep)
#pragma unroll
    for (int b = 0; b < 8; ++b)
      sreg[rep][b] = *(const f32x4*)(sc + (size_t)b * 1024 + rep * 256 + lane * 4);
  const bool fin = j0 >= 24576;
  const int jrel = fin ? (j0 - 24576) : j0;
  const float* Wb = fin ? finw : adaw;
  const float* Bb = fin ? finb : adab;
#pragma unroll
  for (int r = 0; r < 4; ++r) {
    const int j = jrel + r;
    const float* wr = Wb + (size_t)j * 1024;
    float acc[8];
#pragma unroll
    for (int b = 0; b < 8; ++b) acc[b] = 0.f;
#pragma unroll
    for (int rep = 0; rep < 4; ++rep) {
      f32x4 wv = ldnt4(wr + (rep * 64 + lane) * 4);
#pragma unroll
      for (int b = 0; b < 8; ++b) {
        f32x4 s4 = sreg[rep][b];
        acc[b] += wv.x * s4.x + wv.y * s4.y + wv.z * s4.z + wv.w * s4.w;
      }
    }
#pragma unroll
    for (int b = 0; b < 8; ++b) acc[b] = waveAllSum(acc[b]);
    if (lane == 0) {
      const float bb = Bb[j];
      if (fin) {
#pragma unroll
        for (int b = 0; b < 8; ++b) fmods[(size_t)b * 2048 + j] = acc[b] + bb;
      } else {
        const int d = j / 6144;
        const int jj = j - d * 6144;
        float* outb = mods + (size_t)d * 49152;
#pragma unroll
        for (int b = 0; b < 8; ++b) outb[(size_t)b * 6144 + jj] = acc[b] + bb;
      }
    }
  }
}

// ---------------------------------------------------------------------------
// Patch embed
// ---------------------------------------------------------------------------
__global__ __launch_bounds__(256) void patch_kernel(
    const float* __restrict__ x, const float* __restrict__ pw,
    const float* __restrict__ pb, const float* __restrict__ pos,
    float* __restrict__ xc)
{
  const int n = blockIdx.x, b = blockIdx.y, tid = threadIdx.x;
  __shared__ float pv[16];
  if (tid < 16) {
    const int ci = tid >> 2, pi = (tid >> 1) & 1, pj = tid & 1;
    const int i = n >> 4, j = n & 15;
    pv[tid] = x[((size_t)(b * 4 + ci) * 32 + i * 2 + pi) * 32 + j * 2 + pj];
  }
  __syncthreads();
#pragma unroll
  for (int qq = 0; qq < 4; ++qq) {
    const int c = qq * 256 + tid;
    const float4* wr = (const float4*)(pw + (size_t)c * 16);
    float acc = pb[c] + pos[(size_t)n * 1024 + c];
#pragma unroll
    for (int g = 0; g < 4; ++g) {
      float4 w = wr[g];
      acc += w.x * pv[g * 4] + w.y * pv[g * 4 + 1] + w.z * pv[g * 4 + 2] + w.w * pv[g * 4 + 3];
    }
    xc[((size_t)b * 256 + n) * 1024 + c] = acc;
  }
}

// ---------------------------------------------------------------------------
// RMSNorm + adaLN modulate -> fp8 (block per row, coalesced tid*4)
// ---------------------------------------------------------------------------
__global__ __launch_bounds__(256) void normmod8_kernel(
    const float* __restrict__ xc, const float* __restrict__ w,
    const float* __restrict__ mods, int mult_off, int shift_off,
    u8* __restrict__ out)
{
  const int m = blockIdx.x, b = m >> 8, tid = threadIdx.x;
  const float* row = xc + (size_t)m * 1024;
  float4 v = *(const float4*)(row + tid * 4);
  float ss = v.x * v.x + v.y * v.y + v.z * v.z + v.w * v.w;
  ss = waveAllSum(ss);
  __shared__ float red[4];
  if ((tid & 63) == 0) red[tid >> 6] = ss;
  __syncthreads();
  const float tot = red[0] + red[1] + red[2] + red[3];
  const float r = rsqrtf(tot * (1.f / 1024.f) + 1e-6f);
  const float* mb = mods + (size_t)b * 6144;
  const int c = tid * 4;
  float4 wv = *(const float4*)(w + c);
  float4 mu = *(const float4*)(mb + mult_off + c);
  float4 sh = *(const float4*)(mb + shift_off + c);
  u32 p = pk4f8(v.x * r * wv.x * (1.f + mu.x) + sh.x,
                v.y * r * wv.y * (1.f + mu.y) + sh.y,
                v.z * r * wv.z * (1.f + mu.z) + sh.z,
                v.w * r * wv.w * (1.f + mu.w) + sh.w);
  *(u32*)(out + (size_t)m * 1024 + c) = p;
}

// ---------------------------------------------------------------------------
// MFMA attention (bf16 q/k/v in, fp8 out at o[b,n,h,d])
// ---------------------------------------------------------------------------
__global__ __launch_bounds__(256) void attn_kernel(
    const u16* __restrict__ qb, const u16* __restrict__ kb,
    const u16* __restrict__ vb, u8* __restrict__ o)
{
  __shared__ alignas(16) u16 Kt[128][72];
  __shared__ alignas(16) u16 Vtt[64][136];
  __shared__ alignas(16) u16 Pw[4][16][136];
  const int bh = blockIdx.x;
  const int qbase = blockIdx.y * 64;
  const int tid = threadIdx.x;
  const int lane = tid & 63;
  const int wave = tid >> 6;
  const int rl = lane & 15;
  const int kq = (lane >> 4) * 8;
  const int rowg = (lane >> 4) * 4;

  const int q0 = qbase + wave * 16;
  const u16* qsrc = qb + ((size_t)bh * 256 + q0 + rl) * 64 + kq;
  const bf16x8 a0 = *(const bf16x8*)(qsrc);
  const bf16x8 a1 = *(const bf16x8*)(qsrc + 32);

  float m[4], l[4];
  f32x4 oacc[4];
#pragma unroll
  for (int r = 0; r < 4; ++r) { m[r] = -1e30f; l[r] = 0.f; }
#pragma unroll
  for (int dt = 0; dt < 4; ++dt) oacc[dt] = (f32x4){0.f, 0.f, 0.f, 0.f};

  for (int kt = 0; kt < 2; ++kt) {
    __syncthreads();
#pragma unroll
    for (int c = 0; c < 4; ++c) {
      const int flat = c * 256 + tid;
      const int row = flat >> 3;
      const int col = (flat & 7) * 8;
      uint4 v = *(const uint4*)(kb + ((size_t)bh * 256 + kt * 128 + row) * 64 + col);
      *(uint4*)&Kt[row][col] = v;
    }
    {
      const int tt = tid & 63;
      const int dh = tid >> 6;
      const int r0 = tt * 2;
      const u16* s0 = vb + ((size_t)bh * 256 + kt * 128 + r0) * 64 + dh * 16;
      const u16* s1 = s0 + 64;
#pragma unroll
      for (int g = 0; g < 2; ++g) {
        uint4 A = *(const uint4*)(s0 + g * 8);
        uint4 B = *(const uint4*)(s1 + g * 8);
        const u32 aw[4] = {A.x, A.y, A.z, A.w};
        const u32 bw[4] = {B.x, B.y, B.z, B.w};
#pragma unroll
        for (int q = 0; q < 4; ++q) {
          const int d2 = dh * 16 + g * 8 + q * 2;
          const u32 lo = (aw[q] & 0xffffu) | (bw[q] << 16);
          const u32 hi = (aw[q] >> 16) | (bw[q] & 0xffff0000u);
          *(u32*)&Vtt[d2][r0] = lo;
          *(u32*)&Vtt[d2 + 1][r0] = hi;
        }
      }
    }
    __syncthreads();

    f32x4 sacc[8];
#pragma unroll
    for (int t = 0; t < 8; ++t) sacc[t] = (f32x4){0.f, 0.f, 0.f, 0.f};
#pragma unroll
    for (int t = 0; t < 8; ++t) {
      bf16x8 k0 = *(const bf16x8*)&Kt[t * 16 + rl][kq];
      bf16x8 k1 = *(const bf16x8*)&Kt[t * 16 + rl][32 + kq];
      sacc[t] = __builtin_amdgcn_mfma_f32_16x16x32_bf16(a0, k0, sacc[t], 0, 0, 0);
      sacc[t] = __builtin_amdgcn_mfma_f32_16x16x32_bf16(a1, k1, sacc[t], 0, 0, 0);
    }
    float cmax[4];
#pragma unroll
    for (int r = 0; r < 4; ++r) cmax[r] = sacc[0][r];
#pragma unroll
    for (int t = 1; t < 8; ++t)
#pragma unroll
      for (int r = 0; r < 4; ++r) cmax[r] = fmaxf(cmax[r], sacc[t][r]);
#pragma unroll
    for (int off = 1; off < 16; off <<= 1)
#pragma unroll
      for (int r = 0; r < 4; ++r) cmax[r] = fmaxf(cmax[r], __shfl_xor(cmax[r], off, 64));
#pragma unroll
    for (int r = 0; r < 4; ++r) {
      const float mn = fmaxf(m[r], cmax[r]);
      const float corr = __expf((m[r] - mn) * 0.125f);
      l[r] *= corr;
#pragma unroll
      for (int dt = 0; dt < 4; ++dt) oacc[dt][r] *= corr;
      m[r] = mn;
    }
    float lsum[4] = {0.f, 0.f, 0.f, 0.f};
#pragma unroll
    for (int t = 0; t < 8; ++t)
#pragma unroll
      for (int r = 0; r < 4; ++r) {
        const float p = __expf((sacc[t][r] - m[r]) * 0.125f);
        lsum[r] += p;
        Pw[wave][rowg + r][t * 16 + rl] = f2bf(p);
      }
#pragma unroll
    for (int off = 1; off < 16; off <<= 1)
#pragma unroll
      for (int r = 0; r < 4; ++r) lsum[r] += __shfl_xor(lsum[r], off, 64);
#pragma unroll
    for (int r = 0; r < 4; ++r) l[r] += lsum[r];
#pragma unroll
    for (int ks = 0; ks < 4; ++ks) {
      bf16x8 pa = *(const bf16x8*)&Pw[wave][rl][ks * 32 + kq];
#pragma unroll
      for (int dt = 0; dt < 4; ++dt) {
        bf16x8 vf = *(const bf16x8*)&Vtt[dt * 16 + rl][ks * 32 + kq];
        oacc[dt] = __builtin_amdgcn_mfma_f32_16x16x32_bf16(pa, vf, oacc[dt], 0, 0, 0);
      }
    }
  }
  const int b = bh >> 4, h = bh & 15;
#pragma unroll
  for (int r = 0; r < 4; ++r) {
    const float inv = 1.f / l[r];
    const int qrow = q0 + rowg + r;
    u8* dst = o + (((size_t)b * 256 + qrow) * 16 + h) * 64 + rl;
#pragma unroll
    for (int dt = 0; dt < 4; ++dt)
      dst[dt * 16] = (u8)f2f8(oacc[dt][r] * inv);
  }
}

// ---------------------------------------------------------------------------
// Fused final LayerNorm + modulate + final linear + unpatchify.
// ---------------------------------------------------------------------------
__global__ __launch_bounds__(256) void lnfinal_kernel(
    const float* __restrict__ xc, const float* __restrict__ fmods,
    const float* __restrict__ w, const float* __restrict__ bias,
    float* __restrict__ out)
{
  __shared__ alignas(16) u16 xb[16][1024];  // 32KB normalized bf16 rows
  const int tid = threadIdx.x;
  const int lane = tid & 63;
  const int wave = tid >> 6;
  const int mbase = blockIdx.x * 16;
#pragma unroll
  for (int rr = 0; rr < 4; ++rr) {
    const int mloc = wave * 4 + rr;
    const int m = mbase + mloc;
    const int b = m >> 8;
    const float* row = xc + (size_t)m * 1024;
    float4 v[4];
    float s1 = 0.f, s2 = 0.f;
#pragma unroll
    for (int g = 0; g < 4; ++g) {
      v[g] = *(const float4*)(row + g * 256 + lane * 4);
      s1 += v[g].x + v[g].y + v[g].z + v[g].w;
      s2 += v[g].x * v[g].x + v[g].y * v[g].y + v[g].z * v[g].z + v[g].w * v[g].w;
    }
    s1 = waveAllSum(s1);
    s2 = waveAllSum(s2);
    const float mean = s1 * (1.f / 1024.f);
    const float var = s2 * (1.f / 1024.f) - mean * mean;
    const float rstd = rsqrtf(var + 1e-5f);
    const float* mb = fmods + (size_t)b * 2048;
#pragma unroll
    for (int g = 0; g < 4; ++g) {
      const int c = g * 256 + lane * 4;
      float4 sh = *(const float4*)(mb + c);
      float4 sl = *(const float4*)(mb + 1024 + c);
      union { u16 u[4]; uint2 v2; } pk;
      pk.u[0] = f2bf((v[g].x - mean) * rstd * (1.f + sl.x) + sh.x);
      pk.u[1] = f2bf((v[g].y - mean) * rstd * (1.f + sl.y) + sh.y);
      pk.u[2] = f2bf((v[g].z - mean) * rstd * (1.f + sl.z) + sh.z);
      pk.u[3] = f2bf((v[g].w - mean) * rstd * (1.f + sl.w) + sh.w);
      *(uint2*)&xb[mloc][c] = pk.v2;
    }
  }
  __syncthreads();
  const int mloc = tid >> 4;
  const int j = tid & 15;
  const int m = mbase + mloc;
  const float* wr = w + (size_t)j * 1024;
  float acc = 0.f;
  for (int k = 0; k < 1024; k += 8) {
    uint4 xv = *(const uint4*)&xb[mloc][k];
    const u16* xu = (const u16*)&xv;
    float4 w0 = *(const float4*)(wr + k);
    float4 w1 = *(const float4*)(wr + k + 4);
    acc += bf2f(xu[0]) * w0.x + bf2f(xu[1]) * w0.y + bf2f(xu[2]) * w0.z + bf2f(xu[3]) * w0.w;
    acc += bf2f(xu[4]) * w1.x + bf2f(xu[5]) * w1.y + bf2f(xu[6]) * w1.z + bf2f(xu[7]) * w1.w;
  }
  acc += bias[j];
  const int b = m >> 8, n = m & 255;
  const int i = n >> 4, jj = n & 15;
  const int pi = (j >> 3) & 1, pj = (j >> 2) & 1, oc = j & 3;
  out[((size_t)(b * 4 + oc) * 32 + i * 2 + pi) * 32 + jj * 2 + pj] = acc;
}

// ---------------------------------------------------------------------------
extern "C" void kernel_launch(void* const* d_in, const int* in_sizes, int n_in,
                              void* d_out, int out_size, void* d_ws, size_t ws_size,
                              hipStream_t stream) {
  const float* x       = (const float*)d_in[0];
  const int*   y       = (const int*)  d_in[1];
  const float* cfg_s   = (const float*)d_in[2];
  const float* patch_w = (const float*)d_in[3];
  const float* patch_b = (const float*)d_in[4];
  const float* pos_e   = (const float*)d_in[5];
  const float* class_e = (const float*)d_in[6];
  const float* cfg_w1  = (const float*)d_in[7];
  const float* cfg_b1  = (const float*)d_in[8];
  const float* cfg_w2  = (const float*)d_in[9];
  const float* cfg_b2  = (const float*)d_in[10];
  const float* n1w     = (const float*)d_in[11];
  const float* n2w     = (const float*)d_in[12];
  const float* qkvw    = (const float*)d_in[13];
  const float* projw   = (const float*)d_in[14];
  const float* projb   = (const float*)d_in[15];
  const float* qnw     = (const float*)d_in[16];
  const float* knw     = (const float*)d_in[17];
  const float* w1      = (const float*)d_in[18];
  const float* w2      = (const float*)d_in[19];
  const float* w3      = (const float*)d_in[20];
  const float* adaw    = (const float*)d_in[21];
  const float* adab    = (const float*)d_in[22];
  const float* finaw   = (const float*)d_in[23];
  const float* finab   = (const float*)d_in[24];
  const float* flw     = (const float*)d_in[25];
  const float* flb     = (const float*)d_in[26];
  (void)in_sizes; (void)n_in; (void)out_size;

  char* ws = (char*)d_ws;
  const size_t MB = 1024 * 1024;
  if (ws_size < 96 * MB) return;
  float* sc    = (float*)(ws + 32 * 1024);             // 32KB
  float* mods  = (float*)(ws + 64 * 1024);             // 768KB
  float* fmods = (float*)(ws + 64 * 1024 + 786432);    // 64KB
  float* xc    = (float*)(ws + 1 * MB);                // 8MB
  u8*    xm8   = (u8*)   (ws + 9 * MB);                // 2MB
  u16*   qbuf  = (u16*)  (ws + 11 * MB);               // 4MB
  u16*   kbuf  = (u16*)  (ws + 15 * MB);               // 4MB
  u16*   vbuf  = (u16*)  (ws + 19 * MB);               // 4MB
  u8*    h18   = (u8*)   (ws + 23 * MB);               // 5.7MB
  u8*    WB    = (u8*)   (ws + 33 * MB);               // 48.5MB fp8 weights
  const size_t LSTR = 12713984;

  cond_kernel<<<dim3(1024, 8), 64, 0, stream>>>(cfg_s, cfg_w1, cfg_b1, cfg_w2,
                                                cfg_b2, class_e, y, sc);
  modlin_ada_kernel<<<1664, 256, 0, stream>>>(adaw, adab, finaw, finab, sc,
                                              mods, fmods);
  patch_kernel<<<dim3(256, 8), 256, 0, stream>>>(x, patch_w, patch_b, pos_e, xc);
  conv_all_kernel<<<13696, 256, 0, stream>>>(qkvw, projw, w1, w3, w2, WB);
  zt_kernel<<<128, 256, 0, stream>>>(h18);

  for (int d = 0; d < 4; ++d) {
    const float* md = mods + (size_t)d * 49152;
    u8* WL = WB + (size_t)d * LSTR;
    normmod8_kernel<<<2048, 256, 0, stream>>>(xc, n1w + d * 1024, md, 1024, 0, xm8);
    gemm8_t<64, 128, 2><<<768, 256, 0, stream>>>(xm8, 1024, WL, 1024, 8, 32,
                                                 nullptr, nullptr, nullptr,
                                                 qbuf, kbuf, vbuf, nullptr,
                                                 qnw + d * 64, knw + d * 64);
    attn_kernel<<<dim3(128, 4), 256, 0, stream>>>(qbuf, kbuf, vbuf, xm8);
    gemm8_t<64, 64, 1><<<512, 256, 0, stream>>>(xm8, 1024, WL + 3145728, 1024, 8, 32,
                                                xc, md + 2048, projb + d * 1024,
                                                nullptr, nullptr, nullptr, nullptr,
                                                nullptr, nullptr);
    normmod8_kernel<<<2048, 256, 0, stream>>>(xc, n2w + d * 1024, md, 4096, 3072, xm8);
    gemm8_t<64, 128, 3><<<1376, 256, 0, stream>>>(xm8, 1024, WL + 4194304, 1024, 8, 32,
                                                  nullptr, nullptr, nullptr,
                                                  nullptr, nullptr, nullptr, h18,
                                                  nullptr, nullptr);
    gemm8_t<64, 64, 1><<<512, 256, 0, stream>>>(h18, 2816, WL + 9830400, 2816, 22, 32,
                                                xc, md + 5120, nullptr,
                                                nullptr, nullptr, nullptr, nullptr,
                                                nullptr, nullptr);
  }

  lnfinal_kernel<<<128, 256, 0, stream>>>(xc, fmods, flw, flb, (float*)d_out);
}

// Round 17
// 524.383 us; speedup vs baseline: 1.0884x; 1.0171x over previous
//
#include <hip/hip_runtime.h>

typedef unsigned char u8;
typedef unsigned short u16;
typedef unsigned int u32;
typedef float f32x4 __attribute__((ext_vector_type(4)));
typedef u32 u32x4 __attribute__((ext_vector_type(4)));
typedef __bf16 bf16x8 __attribute__((ext_vector_type(8)));

#define DEV __device__ __forceinline__

DEV u16 f2bf(float f) {
  u32 u = __builtin_bit_cast(u32, f);
  u += 0x7fffu + ((u >> 16) & 1u);
  return (u16)(u >> 16);
}
DEV float bf2f(u16 u) { return __builtin_bit_cast(float, (u32)u << 16); }

// f32 -> OCP e4m3fn: hardware cvt_pk when available, software RNE fallback
#if __has_builtin(__builtin_amdgcn_cvt_pk_fp8_f32)
DEV u32 pk4f8(float x, float y, float z, float w) {
  int v = 0;
  v = __builtin_amdgcn_cvt_pk_fp8_f32(x, y, v, false);
  v = __builtin_amdgcn_cvt_pk_fp8_f32(z, w, v, true);
  return (u32)v;
}
DEV u32 f2f8(float f) {
  return (u32)(__builtin_amdgcn_cvt_pk_fp8_f32(f, f, 0, false) & 0xff);
}
#else
DEV u32 f2f8(float f) {
  u32 u = __builtin_bit_cast(u32, f);
  u32 s = (u >> 31) << 7;
  float a = __builtin_fabsf(f);
  if (a >= 448.f) return s | 0x7Eu;
  if (a < 0.015625f) {
    int m = (int)(a * 512.f + 0.5f);
    return s | (u32)m;
  }
  u32 b = __builtin_bit_cast(u32, a);
  b += 0x7FFFFu + ((b >> 20) & 1u);
  u32 E = (b >> 23) - 120u;
  if (E > 15u) return s | 0x7Eu;
  return s | (E << 3) | ((b >> 20) & 7u);
}
DEV u32 pk4f8(float x, float y, float z, float w) {
  return f2f8(x) | (f2f8(y) << 8) | (f2f8(z) << 16) | (f2f8(w) << 24);
}
#endif

// non-temporal LOADS only (read-once f32 weights). Stores stay cached: the
// fp8 WB buffer is re-read by every GEMM and must live in L3.
DEV f32x4 ldnt4(const float* p) {
  return __builtin_nontemporal_load((const f32x4*)p);
}

DEV float waveAllSum(float x) {
#pragma unroll
  for (int off = 32; off > 0; off >>= 1) x += __shfl_xor(x, off, 64);
  return x;
}
DEV float silu_f(float x) { return x / (1.f + __expf(-x)); }

DEV void gll16(const void* g, void* l) {
  __builtin_amdgcn_global_load_lds(
      (const __attribute__((address_space(1))) void*)g,
      (__attribute__((address_space(3))) void*)l, 16, 0, 0);
}

// ---------------------------------------------------------------------------
// FP8 GEMM: C = A_fp8[m,k] * (16*W)_fp8[n,k]^T * (1/16); BM x BN tile,
// BK=128, 4 waves (2x2), dbuf global_load_lds + counted vmcnt.
// LDS rows 128B as long[16]; 16B-chunk XOR swizzle by row&7 on global SOURCE
// (linear LDS dest, rule #21) and on the ds_read index.
// EPI: 1 = residual RX += gm*(acc*S+bias); 2 = qk-RMSNorm+RoPE+v -> bf16
// q/k/v; 3 = SwiGLU pair-fuse -> h1 fp8 (w1/w3 interleaved 16-unit groups).
// ---------------------------------------------------------------------------
template<int BM, int BN, int EPI>
__global__ __launch_bounds__(256, (BM == 128 ? 2 : ((BM + BN) == 128 ? 4 : 3)))
void gemm8_t(
    const u8* __restrict__ A, int lda,
    const u8* __restrict__ W, int ldw,
    int Ksteps, int nbx,
    float* __restrict__ RX, const float* __restrict__ gmods,
    const float* __restrict__ bias,
    u16* __restrict__ ob0, u16* __restrict__ ob1, u16* __restrict__ ob2,
    u8* __restrict__ h1o,
    const float* __restrict__ nw_q, const float* __restrict__ nw_k)
{
  constexpr int MI = BM / 32;           // 16-row acc tiles per wave
  constexpr int NJ = BN / 32;           // 16-col acc tiles per wave
  constexpr int LOADS = (BM + BN) / 32; // gll16 per lane per stage
  __shared__ long As[2][BM][16];
  __shared__ long Ws[2][BN][16];
  const int tid = threadIdx.x;
  const int lane = tid & 63;
  const int wave = tid >> 6;
  const int nwg = gridDim.x;
  const int cpx = nwg >> 3;
  const int fb = blockIdx.x;
  const int idx = (fb & 7) * cpx + (fb >> 3);
  const int m0 = (idx % nbx) * BM;
  const int n0 = (idx / nbx) * BN;
  const int wm = (wave >> 1) * (BM / 2);
  const int wn = (wave & 1) * (BN / 2);
  const int rl = lane & 15;
  const int qq = lane >> 4;            // 0..3
  const u8* Abase = A + (size_t)m0 * lda;
  const u8* Wbase = W + (size_t)n0 * ldw;

  f32x4 acc[MI][NJ];
#pragma unroll
  for (int i = 0; i < MI; ++i)
#pragma unroll
    for (int j = 0; j < NJ; ++j) acc[i][j] = (f32x4){0.f, 0.f, 0.f, 0.f};

  auto STAGE = [&](int buf, int k0) {
#pragma unroll
    for (int c = 0; c < BM / 32; ++c) {
      const int flat = c * 256 + tid;
      const int row = flat >> 3;
      const int ch = flat & 7;
      gll16(Abase + (size_t)row * lda + k0 + ((ch ^ (row & 7)) << 4),
            &As[buf][row][ch * 2]);
    }
#pragma unroll
    for (int c = 0; c < BN / 32; ++c) {
      const int flat = c * 256 + tid;
      const int row = flat >> 3;
      const int ch = flat & 7;
      gll16(Wbase + (size_t)row * ldw + k0 + ((ch ^ (row & 7)) << 4),
            &Ws[buf][row][ch * 2]);
    }
  };

  STAGE(0, 0);
  for (int kt = 0; kt < Ksteps; ++kt) {
    const int buf = kt & 1;
    if (kt + 1 < Ksteps) {
      STAGE(buf ^ 1, (kt + 1) * 128);
      if constexpr (LOADS == 8)
        asm volatile("s_waitcnt vmcnt(8)" ::: "memory");
      else if constexpr (LOADS == 6)
        asm volatile("s_waitcnt vmcnt(6)" ::: "memory");
      else
        asm volatile("s_waitcnt vmcnt(4)" ::: "memory");
    } else {
      asm volatile("s_waitcnt vmcnt(0)" ::: "memory");
    }
    __builtin_amdgcn_s_barrier();
    __builtin_amdgcn_sched_barrier(0);
#pragma unroll
    for (int kk = 0; kk < 4; ++kk) {
      const int lo = (((kk * 2 + (qq >> 1)) ^ (rl & 7)) << 1) | (qq & 1);
      long af[MI];
#pragma unroll
      for (int i = 0; i < MI; ++i) af[i] = As[buf][wm + i * 16 + rl][lo];
      long bw[NJ];
#pragma unroll
      for (int j = 0; j < NJ; ++j) bw[j] = Ws[buf][wn + j * 16 + rl][lo];
#pragma unroll
      for (int i = 0; i < MI; ++i)
#pragma unroll
        for (int j = 0; j < NJ; ++j)
          acc[i][j] = __builtin_amdgcn_mfma_f32_16x16x32_fp8_fp8(af[i], bw[j], acc[i][j], 0, 0, 0);
    }
    __builtin_amdgcn_sched_barrier(0);
    __builtin_amdgcn_s_barrier();
  }

  constexpr float S = 0.0625f;  // 1/16 weight descale
  const int rq = qq * 4;
  if constexpr (EPI == 1) {
    const int b = m0 >> 8;
    const float* gm = gmods + (size_t)b * 6144;
#pragma unroll
    for (int j = 0; j < NJ; ++j) {
      const int n = n0 + wn + j * 16 + rl;
      const float g = gm[n];
      const float bv = bias ? bias[n] : 0.f;
#pragma unroll
      for (int i = 0; i < MI; ++i) {
        const int mrow = m0 + wm + i * 16 + rq;
#pragma unroll
        for (int r = 0; r < 4; ++r) {
          float* p = RX + (size_t)(mrow + r) * 1024 + n;
          *p += g * (acc[i][j][r] * S + bv);
        }
      }
    }
  } else if constexpr (EPI == 2) {
    const int region = n0 >> 10;  // 0=q,1=k,2=v
    const int h = ((n0 + wn) >> 6) & 15;
    const int bh = (m0 >> 8) * 16 + h;
    if (region == 2) {
#pragma unroll
      for (int i = 0; i < MI; ++i)
#pragma unroll
        for (int r = 0; r < 4; ++r) {
          const int token = (m0 + wm + i * 16 + rq + r) & 255;
          u16* dst = ob2 + ((size_t)bh * 256 + token) * 64 + rl;
#pragma unroll
          for (int j = 0; j < 4; ++j) dst[j * 16] = f2bf(acc[i][j][r] * S);
        }
    } else {
      const float* nw = region ? nw_k : nw_q;
      u16* obuf = region ? ob1 : ob0;
      float wv[4];
#pragma unroll
      for (int j = 0; j < 4; ++j) wv[j] = nw[j * 16 + rl];
      const float f0 = __powf(10000.f, -(float)(2 * rl) * (1.f / 64.f));
      const float f1 = __powf(10000.f, -(float)(2 * (16 + rl)) * (1.f / 64.f));
#pragma unroll
      for (int i = 0; i < MI; ++i) {
        float va[4][4];
        float ss[4];
#pragma unroll
        for (int r = 0; r < 4; ++r) {
          ss[r] = 0.f;
#pragma unroll
          for (int j = 0; j < 4; ++j) {
            va[j][r] = acc[i][j][r] * S;
            ss[r] += va[j][r] * va[j][r];
          }
        }
#pragma unroll
        for (int off = 1; off < 16; off <<= 1)
#pragma unroll
          for (int r = 0; r < 4; ++r) ss[r] += __shfl_xor(ss[r], off, 64);
#pragma unroll
        for (int r = 0; r < 4; ++r) {
          const int token = (m0 + wm + i * 16 + rq + r) & 255;
          const float rms = rsqrtf(ss[r] * (1.f / 64.f) + 1e-6f);
          float nv[4];
#pragma unroll
          for (int j = 0; j < 4; ++j) nv[j] = va[j][r] * rms * wv[j];
          float s0, c0, s1, c1;
          __sincosf((float)token * f0, &s0, &c0);
          __sincosf((float)token * f1, &s1, &c1);
          u16* dst = obuf + ((size_t)bh * 256 + token) * 64 + rl;
          dst[0]  = f2bf(nv[0] * c0 - nv[2] * s0);
          dst[16] = f2bf(nv[1] * c1 - nv[3] * s1);
          dst[32] = f2bf(nv[2] * c0 + nv[0] * s0);
          dst[48] = f2bf(nv[3] * c1 + nv[1] * s1);
        }
      }
    }
  } else if constexpr (EPI == 3) {
    const int ubase = ((n0 + wn) >> 1) + rl;
#pragma unroll
    for (int i = 0; i < MI; ++i)
#pragma unroll
      for (int r = 0; r < 4; ++r) {
        const int row = m0 + wm + i * 16 + rq + r;
        u8* dst = h1o + (size_t)row * 2816 + ubase;
#pragma unroll
        for (int p = 0; p < 2; ++p) {
          const float a = acc[i][2 * p][r] * S;
          const float b3 = acc[i][2 * p + 1][r] * S;
          dst[p * 16] = (u8)f2f8(silu_f(a) * b3);
        }
      }
  }
}

// ---------------------------------------------------------------------------
// Merged weight conversion v7: v6 + absorbed h1-pad zeroing (blocks >= 13696).
// Non-temporal f32 loads (read-once) + CACHED LDS-packed uint4 stores.
// Grid 13824: [0,3072) qkv | [3072,4096) proj | [4096,9600) w13 |
//             [9600,13696) w2 | [13696,13824) h1 pad zero.
// ---------------------------------------------------------------------------
__global__ __launch_bounds__(256) void conv_all_kernel(
    const float* __restrict__ qkvw, const float* __restrict__ projw,
    const float* __restrict__ w1, const float* __restrict__ w3,
    const float* __restrict__ w2, u8* __restrict__ WB,
    u8* __restrict__ h1pad)
{
  __shared__ u32 lbuf[1024];
  const int bid = blockIdx.x;
  const int tid = threadIdx.x;
  if (bid < 4096) {
    const float* src;
    u8* dstbase;
    if (bid < 3072) {
      const int d = bid / 768, rb = bid - d * 768;
      src = qkvw + (size_t)d * 3145728 + (size_t)rb * 4096;
      dstbase = WB + (size_t)d * 12713984 + (size_t)rb * 4096;
    } else {
      const int d = (bid - 3072) >> 8, rb = (bid - 3072) & 255;
      src = projw + (size_t)d * 1048576 + (size_t)rb * 4096;
      dstbase = WB + (size_t)d * 12713984 + 3145728 + (size_t)rb * 4096;
    }
    f32x4 v[4];
#pragma unroll
    for (int k = 0; k < 4; ++k)
      v[k] = ldnt4(src + (k * 256 + tid) * 4);
#pragma unroll
    for (int k = 0; k < 4; ++k)
      lbuf[k * 256 + tid] = pk4f8(v[k].x * 16.f, v[k].y * 16.f, v[k].z * 16.f, v[k].w * 16.f);
    __syncthreads();
    *(u32x4*)(dstbase + tid * 16) = *(u32x4*)&lbuf[tid * 4];
  } else if (bid < 9600) {
    const int base = (bid - 4096) * 4 + (tid >> 6);
    const int d = base / 5504, rW = base % 5504;
    const int t = rW >> 5, s = rW & 31;
    const int unit = 16 * t + (s & 15);
    const int lane = tid & 63;
    const int lrow = tid >> 6;
    if (unit < 2730) {
      const float* src = ((s < 16) ? w1 : w3) + (size_t)d * 2795520 + (size_t)unit * 1024;
      f32x4 v[4];
#pragma unroll
      for (int rep = 0; rep < 4; ++rep)
        v[rep] = ldnt4(src + rep * 256 + lane * 4);
#pragma unroll
      for (int rep = 0; rep < 4; ++rep)
        lbuf[lrow * 256 + rep * 64 + lane] =
            pk4f8(v[rep].x * 16.f, v[rep].y * 16.f, v[rep].z * 16.f, v[rep].w * 16.f);
    } else {
#pragma unroll
      for (int rep = 0; rep < 4; ++rep)
        lbuf[lrow * 256 + rep * 64 + lane] = 0;
    }
    __syncthreads();
    u8* dst = WB + (size_t)d * 12713984 + 4194304 + (size_t)rW * 1024 + lane * 16;
    *(u32x4*)dst = *(u32x4*)&lbuf[lrow * 256 + lane * 4];
  } else if (bid < 13696) {
    const int rc = bid - 9600;
    const int d = rc >> 10, r = rc & 1023;
    const float* src = w2 + (size_t)d * 2795520 + (size_t)r * 2730;
    u8* dst = WB + (size_t)d * 12713984 + 9830400 + (size_t)r * 2816;
    u32 o[3];
#pragma unroll
    for (int it = 0; it < 3; ++it) {
      const int c = tid * 4 + it * 1024;
      if (c + 4 <= 2730) {
        f32x4 vv = ldnt4(src + c);  // rows 4B-aligned; dwordx4 ok
        o[it] = pk4f8(vv.x * 16.f, vv.y * 16.f, vv.z * 16.f, vv.w * 16.f);
      } else {
        float v[4];
#pragma unroll
        for (int i = 0; i < 4; ++i)
          v[i] = (c + i < 2730) ? src[c + i] * 16.f : 0.f;
        o[it] = pk4f8(v[0], v[1], v[2], v[3]);
      }
    }
#pragma unroll
    for (int it = 0; it < 3; ++it) {
      const int c = tid * 4 + it * 1024;
      if (c < 2816) lbuf[c >> 2] = o[it];
    }
    __syncthreads();
    if (tid < 176)
      *(u32x4*)(dst + tid * 16) = *(u32x4*)&lbuf[tid * 4];
  } else {
    // h1 pad zero: rows 0..2047, cols [2752,2816)
    const int idx = (bid - 13696) * 256 + tid;  // 32768
    const int row = idx >> 4, c = idx & 15;
    *(u32*)(h1pad + (size_t)row * 2816 + 2752 + c * 4) = 0;
  }
}

// ---------------------------------------------------------------------------
// Conditioning
// ---------------------------------------------------------------------------
__global__ __launch_bounds__(64) void cond_kernel(
    const float* __restrict__ cfg_s, const float* __restrict__ w1,
    const float* __restrict__ b1, const float* __restrict__ w2,
    const float* __restrict__ b2, const float* __restrict__ ce,
    const int* __restrict__ y, float* __restrict__ sc)
{
  const int j = blockIdx.x, b = blockIdx.y, lane = threadIdx.x;
  const float s = cfg_s[b];
  const float4* wr = (const float4*)(w2 + (size_t)j * 1024);
  const float4* w1r = (const float4*)w1;
  const float4* b1r = (const float4*)b1;
  float acc = 0.f;
#pragma unroll
  for (int rep = 0; rep < 4; ++rep) {
    const int c = rep * 64 + lane;
    float4 w = wr[c];
    float4 a = w1r[c];
    float4 bb = b1r[c];
    acc += w.x * silu_f(s * a.x + bb.x) + w.y * silu_f(s * a.y + bb.y) +
           w.z * silu_f(s * a.z + bb.z) + w.w * silu_f(s * a.w + bb.w);
  }
  acc = waveAllSum(acc);
  if (lane == 0) {
    float v = ce[(size_t)y[b] * 1024 + j] + acc + b2[j];
    sc[(size_t)b * 1024 + j] = silu_f(v);
  }
}

// ada + final modulations in one dispatch: grid 1664 blocks x 256 thr.
// All 16 weight-row nt-loads for the wave's 4 rows are hoisted ahead of the
// FMA/reduce phase (deep memory ILP); sc slice cached in registers.
__global__ __launch_bounds__(256, 2) void modlin_ada_kernel(
    const float* __restrict__ adaw, const float* __restrict__ adab,
    const float* __restrict__ finw, const float* __restrict__ finb,
    const float* __restrict__ sc, float* __restrict__ mods,
    float* __restrict__ fmods)
{
  const int tid = threadIdx.x;
  const int lane = tid & 63;
  const int wave = tid >> 6;
  const int j0 = blockIdx.x * 16 + wave * 4;
  f32x4 sreg[4][8];
#pragma unroll
  for (int rep = 0; rep < 4; ++rep)
#pragma unroll
    for (int b = 0; b < 8; ++b)
      sreg[rep][b] = *(const f32x4*)(sc + (size_t)b * 1024 + rep * 256 + lane * 4);
  const bool fin = j0 >= 24576;
  const int jrel = fin ? (j0 - 24576) : j0;
  const float* Wb = fin ? finw : adaw;
  const float* Bb = fin ? finb : adab;
  f32x4 wv[4][4];
#pragma unroll
  for (int r = 0; r < 4; ++r)
#pragma unroll
    for (int rep = 0; rep < 4; ++rep)
      wv[r][rep] = ldnt4(Wb + (size_t)(jrel + r) * 1024 + (rep * 64 + lane) * 4);
#pragma unroll
  for (int r = 0; r < 4; ++r) {
    const int j = jrel + r;
    float acc[8];
#pragma unroll
    for (int b = 0; b < 8; ++b) acc[b] = 0.f;
#pragma unroll
    for (int rep = 0; rep < 4; ++rep) {
      f32x4 w4 = wv[r][rep];
#pragma unroll
      for (int b = 0; b < 8; ++b) {
        f32x4 s4 = sreg[rep][b];
        acc[b] += w4.x * s4.x + w4.y * s4.y + w4.z * s4.z + w4.w * s4.w;
      }
    }
#pragma unroll
    for (int b = 0; b < 8; ++b) acc[b] = waveAllSum(acc[b]);
    if (lane == 0) {
      const float bb = Bb[j];
      if (fin) {
#pragma unroll
        for (int b = 0; b < 8; ++b) fmods[(size_t)b * 2048 + j] = acc[b] + bb;
      } else {
        const int d = j / 6144;
        const int jj = j - d * 6144;
        float* outb = mods + (size_t)d * 49152;
#pragma unroll
        for (int b = 0; b < 8; ++b) outb[(size_t)b * 6144 + jj] = acc[b] + bb;
      }
    }
  }
}

// ---------------------------------------------------------------------------
// Patch embed
// ---------------------------------------------------------------------------
__global__ __launch_bounds__(256) void patch_kernel(
    const float* __restrict__ x, const float* __restrict__ pw,
    const float* __restrict__ pb, const float* __restrict__ pos,
    float* __restrict__ xc)
{
  const int n = blockIdx.x, b = blockIdx.y, tid = threadIdx.x;
  __shared__ float pv[16];
  if (tid < 16) {
    const int ci = tid >> 2, pi = (tid >> 1) & 1, pj = tid & 1;
    const int i = n >> 4, j = n & 15;
    pv[tid] = x[((size_t)(b * 4 + ci) * 32 + i * 2 + pi) * 32 + j * 2 + pj];
  }
  __syncthreads();
#pragma unroll
  for (int qq = 0; qq < 4; ++qq) {
    const int c = qq * 256 + tid;
    const float4* wr = (const float4*)(pw + (size_t)c * 16);
    float acc = pb[c] + pos[(size_t)n * 1024 + c];
#pragma unroll
    for (int g = 0; g < 4; ++g) {
      float4 w = wr[g];
      acc += w.x * pv[g * 4] + w.y * pv[g * 4 + 1] + w.z * pv[g * 4 + 2] + w.w * pv[g * 4 + 3];
    }
    xc[((size_t)b * 256 + n) * 1024 + c] = acc;
  }
}

// ---------------------------------------------------------------------------
// RMSNorm + adaLN modulate -> fp8 (block per row, coalesced tid*4)
// ---------------------------------------------------------------------------
__global__ __launch_bounds__(256) void normmod8_kernel(
    const float* __restrict__ xc, const float* __restrict__ w,
    const float* __restrict__ mods, int mult_off, int shift_off,
    u8* __restrict__ out)
{
  const int m = blockIdx.x, b = m >> 8, tid = threadIdx.x;
  const float* row = xc + (size_t)m * 1024;
  float4 v = *(const float4*)(row + tid * 4);
  float ss = v.x * v.x + v.y * v.y + v.z * v.z + v.w * v.w;
  ss = waveAllSum(ss);
  __shared__ float red[4];
  if ((tid & 63) == 0) red[tid >> 6] = ss;
  __syncthreads();
  const float tot = red[0] + red[1] + red[2] + red[3];
  const float r = rsqrtf(tot * (1.f / 1024.f) + 1e-6f);
  const float* mb = mods + (size_t)b * 6144;
  const int c = tid * 4;
  float4 wv = *(const float4*)(w + c);
  float4 mu = *(const float4*)(mb + mult_off + c);
  float4 sh = *(const float4*)(mb + shift_off + c);
  u32 p = pk4f8(v.x * r * wv.x * (1.f + mu.x) + sh.x,
                v.y * r * wv.y * (1.f + mu.y) + sh.y,
                v.z * r * wv.z * (1.f + mu.z) + sh.z,
                v.w * r * wv.w * (1.f + mu.w) + sh.w);
  *(u32*)(out + (size_t)m * 1024 + c) = p;
}

// ---------------------------------------------------------------------------
// MFMA attention (bf16 q/k/v in, fp8 out at o[b,n,h,d])
// ---------------------------------------------------------------------------
__global__ __launch_bounds__(256) void attn_kernel(
    const u16* __restrict__ qb, const u16* __restrict__ kb,
    const u16* __restrict__ vb, u8* __restrict__ o)
{
  __shared__ alignas(16) u16 Kt[128][72];
  __shared__ alignas(16) u16 Vtt[64][136];
  __shared__ alignas(16) u16 Pw[4][16][136];
  const int bh = blockIdx.x;
  const int qbase = blockIdx.y * 64;
  const int tid = threadIdx.x;
  const int lane = tid & 63;
  const int wave = tid >> 6;
  const int rl = lane & 15;
  const int kq = (lane >> 4) * 8;
  const int rowg = (lane >> 4) * 4;

  const int q0 = qbase + wave * 16;
  const u16* qsrc = qb + ((size_t)bh * 256 + q0 + rl) * 64 + kq;
  const bf16x8 a0 = *(const bf16x8*)(qsrc);
  const bf16x8 a1 = *(const bf16x8*)(qsrc + 32);

  float m[4], l[4];
  f32x4 oacc[4];
#pragma unroll
  for (int r = 0; r < 4; ++r) { m[r] = -1e30f; l[r] = 0.f; }
#pragma unroll
  for (int dt = 0; dt < 4; ++dt) oacc[dt] = (f32x4){0.f, 0.f, 0.f, 0.f};

  for (int kt = 0; kt < 2; ++kt) {
    __syncthreads();
#pragma unroll
    for (int c = 0; c < 4; ++c) {
      const int flat = c * 256 + tid;
      const int row = flat >> 3;
      const int col = (flat & 7) * 8;
      uint4 v = *(const uint4*)(kb + ((size_t)bh * 256 + kt * 128 + row) * 64 + col);
      *(uint4*)&Kt[row][col] = v;
    }
    {
      const int tt = tid & 63;
      const int dh = tid >> 6;
      const int r0 = tt * 2;
      const u16* s0 = vb + ((size_t)bh * 256 + kt * 128 + r0) * 64 + dh * 16;
      const u16* s1 = s0 + 64;
#pragma unroll
      for (int g = 0; g < 2; ++g) {
        uint4 A = *(const uint4*)(s0 + g * 8);
        uint4 B = *(const uint4*)(s1 + g * 8);
        const u32 aw[4] = {A.x, A.y, A.z, A.w};
        const u32 bw[4] = {B.x, B.y, B.z, B.w};
#pragma unroll
        for (int q = 0; q < 4; ++q) {
          const int d2 = dh * 16 + g * 8 + q * 2;
          const u32 lo = (aw[q] & 0xffffu) | (bw[q] << 16);
          const u32 hi = (aw[q] >> 16) | (bw[q] & 0xffff0000u);
          *(u32*)&Vtt[d2][r0] = lo;
          *(u32*)&Vtt[d2 + 1][r0] = hi;
        }
      }
    }
    __syncthreads();

    f32x4 sacc[8];
#pragma unroll
    for (int t = 0; t < 8; ++t) sacc[t] = (f32x4){0.f, 0.f, 0.f, 0.f};
#pragma unroll
    for (int t = 0; t < 8; ++t) {
      bf16x8 k0 = *(const bf16x8*)&Kt[t * 16 + rl][kq];
      bf16x8 k1 = *(const bf16x8*)&Kt[t * 16 + rl][32 + kq];
      sacc[t] = __builtin_amdgcn_mfma_f32_16x16x32_bf16(a0, k0, sacc[t], 0, 0, 0);
      sacc[t] = __builtin_amdgcn_mfma_f32_16x16x32_bf16(a1, k1, sacc[t], 0, 0, 0);
    }
    float cmax[4];
#pragma unroll
    for (int r = 0; r < 4; ++r) cmax[r] = sacc[0][r];
#pragma unroll
    for (int t = 1; t < 8; ++t)
#pragma unroll
      for (int r = 0; r < 4; ++r) cmax[r] = fmaxf(cmax[r], sacc[t][r]);
#pragma unroll
    for (int off = 1; off < 16; off <<= 1)
#pragma unroll
      for (int r = 0; r < 4; ++r) cmax[r] = fmaxf(cmax[r], __shfl_xor(cmax[r], off, 64));
#pragma unroll
    for (int r = 0; r < 4; ++r) {
      const float mn = fmaxf(m[r], cmax[r]);
      const float corr = __expf((m[r] - mn) * 0.125f);
      l[r] *= corr;
#pragma unroll
      for (int dt = 0; dt < 4; ++dt) oacc[dt][r] *= corr;
      m[r] = mn;
    }
    float lsum[4] = {0.f, 0.f, 0.f, 0.f};
#pragma unroll
    for (int t = 0; t < 8; ++t)
#pragma unroll
      for (int r = 0; r < 4; ++r) {
        const float p = __expf((sacc[t][r] - m[r]) * 0.125f);
        lsum[r] += p;
        Pw[wave][rowg + r][t * 16 + rl] = f2bf(p);
      }
#pragma unroll
    for (int off = 1; off < 16; off <<= 1)
#pragma unroll
      for (int r = 0; r < 4; ++r) lsum[r] += __shfl_xor(lsum[r], off, 64);
#pragma unroll
    for (int r = 0; r < 4; ++r) l[r] += lsum[r];
#pragma unroll
    for (int ks = 0; ks < 4; ++ks) {
      bf16x8 pa = *(const bf16x8*)&Pw[wave][rl][ks * 32 + kq];
#pragma unroll
      for (int dt = 0; dt < 4; ++dt) {
        bf16x8 vf = *(const bf16x8*)&Vtt[dt * 16 + rl][ks * 32 + kq];
        oacc[dt] = __builtin_amdgcn_mfma_f32_16x16x32_bf16(pa, vf, oacc[dt], 0, 0, 0);
      }
    }
  }
  const int b = bh >> 4, h = bh & 15;
#pragma unroll
  for (int r = 0; r < 4; ++r) {
    const float inv = 1.f / l[r];
    const int qrow = q0 + rowg + r;
    u8* dst = o + (((size_t)b * 256 + qrow) * 16 + h) * 64 + rl;
#pragma unroll
    for (int dt = 0; dt < 4; ++dt)
      dst[dt * 16] = (u8)f2f8(oacc[dt][r] * inv);
  }
}

// ---------------------------------------------------------------------------
// Fused final LayerNorm + modulate + final linear + unpatchify.
// ---------------------------------------------------------------------------
__global__ __launch_bounds__(256) void lnfinal_kernel(
    const float* __restrict__ xc, const float* __restrict__ fmods,
    const float* __restrict__ w, const float* __restrict__ bias,
    float* __restrict__ out)
{
  __shared__ alignas(16) u16 xb[16][1024];  // 32KB normalized bf16 rows
  const int tid = threadIdx.x;
  const int lane = tid & 63;
  const int wave = tid >> 6;
  const int mbase = blockIdx.x * 16;
#pragma unroll
  for (int rr = 0; rr < 4; ++rr) {
    const int mloc = wave * 4 + rr;
    const int m = mbase + mloc;
    const int b = m >> 8;
    const float* row = xc + (size_t)m * 1024;
    float4 v[4];
    float s1 = 0.f, s2 = 0.f;
#pragma unroll
    for (int g = 0; g < 4; ++g) {
      v[g] = *(const float4*)(row + g * 256 + lane * 4);
      s1 += v[g].x + v[g].y + v[g].z + v[g].w;
      s2 += v[g].x * v[g].x + v[g].y * v[g].y + v[g].z * v[g].z + v[g].w * v[g].w;
    }
    s1 = waveAllSum(s1);
    s2 = waveAllSum(s2);
    const float mean = s1 * (1.f / 1024.f);
    const float var = s2 * (1.f / 1024.f) - mean * mean;
    const float rstd = rsqrtf(var + 1e-5f);
    const float* mb = fmods + (size_t)b * 2048;
#pragma unroll
    for (int g = 0; g < 4; ++g) {
      const int c = g * 256 + lane * 4;
      float4 sh = *(const float4*)(mb + c);
      float4 sl = *(const float4*)(mb + 1024 + c);
      union { u16 u[4]; uint2 v2; } pk;
      pk.u[0] = f2bf((v[g].x - mean) * rstd * (1.f + sl.x) + sh.x);
      pk.u[1] = f2bf((v[g].y - mean) * rstd * (1.f + sl.y) + sh.y);
      pk.u[2] = f2bf((v[g].z - mean) * rstd * (1.f + sl.z) + sh.z);
      pk.u[3] = f2bf((v[g].w - mean) * rstd * (1.f + sl.w) + sh.w);
      *(uint2*)&xb[mloc][c] = pk.v2;
    }
  }
  __syncthreads();
  const int mloc = tid >> 4;
  const int j = tid & 15;
  const int m = mbase + mloc;
  const float* wr = w + (size_t)j * 1024;
  float acc = 0.f;
  for (int k = 0; k < 1024; k += 8) {
    uint4 xv = *(const uint4*)&xb[mloc][k];
    const u16* xu = (const u16*)&xv;
    float4 w0 = *(const float4*)(wr + k);
    float4 w1 = *(const float4*)(wr + k + 4);
    acc += bf2f(xu[0]) * w0.x + bf2f(xu[1]) * w0.y + bf2f(xu[2]) * w0.z + bf2f(xu[3]) * w0.w;
    acc += bf2f(xu[4]) * w1.x + bf2f(xu[5]) * w1.y + bf2f(xu[6]) * w1.z + bf2f(xu[7]) * w1.w;
  }
  acc += bias[j];
  const int b = m >> 8, n = m & 255;
  const int i = n >> 4, jj = n & 15;
  const int pi = (j >> 3) & 1, pj = (j >> 2) & 1, oc = j & 3;
  out[((size_t)(b * 4 + oc) * 32 + i * 2 + pi) * 32 + jj * 2 + pj] = acc;
}

// ---------------------------------------------------------------------------
extern "C" void kernel_launch(void* const* d_in, const int* in_sizes, int n_in,
                              void* d_out, int out_size, void* d_ws, size_t ws_size,
                              hipStream_t stream) {
  const float* x       = (const float*)d_in[0];
  const int*   y       = (const int*)  d_in[1];
  const float* cfg_s   = (const float*)d_in[2];
  const float* patch_w = (const float*)d_in[3];
  const float* patch_b = (const float*)d_in[4];
  const float* pos_e   = (const float*)d_in[5];
  const float* class_e = (const float*)d_in[6];
  const float* cfg_w1  = (const float*)d_in[7];
  const float* cfg_b1  = (const float*)d_in[8];
  const float* cfg_w2  = (const float*)d_in[9];
  const float* cfg_b2  = (const float*)d_in[10];
  const float* n1w     = (const float*)d_in[11];
  const float* n2w     = (const float*)d_in[12];
  const float* qkvw    = (const float*)d_in[13];
  const float* projw   = (const float*)d_in[14];
  const float* projb   = (const float*)d_in[15];
  const float* qnw     = (const float*)d_in[16];
  const float* knw     = (const float*)d_in[17];
  const float* w1      = (const float*)d_in[18];
  const float* w2      = (const float*)d_in[19];
  const float* w3      = (const float*)d_in[20];
  const float* adaw    = (const float*)d_in[21];
  const float* adab    = (const float*)d_in[22];
  const float* finaw   = (const float*)d_in[23];
  const float* finab   = (const float*)d_in[24];
  const float* flw     = (const float*)d_in[25];
  const float* flb     = (const float*)d_in[26];
  (void)in_sizes; (void)n_in; (void)out_size;

  char* ws = (char*)d_ws;
  const size_t MB = 1024 * 1024;
  if (ws_size < 96 * MB) return;
  float* sc    = (float*)(ws + 32 * 1024);             // 32KB
  float* mods  = (float*)(ws + 64 * 1024);             // 768KB
  float* fmods = (float*)(ws + 64 * 1024 + 786432);    // 64KB
  float* xc    = (float*)(ws + 1 * MB);                // 8MB
  u8*    xm8   = (u8*)   (ws + 9 * MB);                // 2MB
  u16*   qbuf  = (u16*)  (ws + 11 * MB);               // 4MB
  u16*   kbuf  = (u16*)  (ws + 15 * MB);               // 4MB
  u16*   vbuf  = (u16*)  (ws + 19 * MB);               // 4MB
  u8*    h18   = (u8*)   (ws + 23 * MB);               // 5.7MB
  u8*    WB    = (u8*)   (ws + 33 * MB);               // 48.5MB fp8 weights
  const size_t LSTR = 12713984;

  cond_kernel<<<dim3(1024, 8), 64, 0, stream>>>(cfg_s, cfg_w1, cfg_b1, cfg_w2,
                                                cfg_b2, class_e, y, sc);
  modlin_ada_kernel<<<1664, 256, 0, stream>>>(adaw, adab, finaw, finab, sc,
                                              mods, fmods);
  patch_kernel<<<dim3(256, 8), 256, 0, stream>>>(x, patch_w, patch_b, pos_e, xc);
  conv_all_kernel<<<13824, 256, 0, stream>>>(qkvw, projw, w1, w3, w2, WB, h18);

  for (int d = 0; d < 4; ++d) {
    const float* md = mods + (size_t)d * 49152;
    u8* WL = WB + (size_t)d * LSTR;
    normmod8_kernel<<<2048, 256, 0, stream>>>(xc, n1w + d * 1024, md, 1024, 0, xm8);
    gemm8_t<64, 128, 2><<<768, 256, 0, stream>>>(xm8, 1024, WL, 1024, 8, 32,
                                                 nullptr, nullptr, nullptr,
                                                 qbuf, kbuf, vbuf, nullptr,
                                                 qnw + d * 64, knw + d * 64);
    attn_kernel<<<dim3(128, 4), 256, 0, stream>>>(qbuf, kbuf, vbuf, xm8);
    gemm8_t<64, 64, 1><<<512, 256, 0, stream>>>(xm8, 1024, WL + 3145728, 1024, 8, 32,
                                                xc, md + 2048, projb + d * 1024,
                                                nullptr, nullptr, nullptr, nullptr,
                                                nullptr, nullptr);
    normmod8_kernel<<<2048, 256, 0, stream>>>(xc, n2w + d * 1024, md, 4096, 3072, xm8);
    gemm8_t<64, 128, 3><<<1376, 256, 0, stream>>>(xm8, 1024, WL + 4194304, 1024, 8, 32,
                                                  nullptr, nullptr, nullptr,
                                                  nullptr, nullptr, nullptr, h18,
                                                  nullptr, nullptr);
    gemm8_t<64, 64, 1><<<512, 256, 0, stream>>>(h18, 2816, WL + 9830400, 2816, 22, 32,
                                                xc, md + 5120, nullptr,
                                                nullptr, nullptr, nullptr, nullptr,
                                                nullptr, nullptr);
  }

  lnfinal_kernel<<<128, 256, 0, stream>>>(xc, fmods, flw, flb, (float*)d_out);
}